// Round 7
// baseline (1976.405 us; speedup 1.0000x reference)
//
#include <hip/hip_runtime.h>
#include <stdint.h>

typedef unsigned long long u64;
typedef unsigned int u32;
typedef unsigned char u8;

// ---------------------------------------------------------------------------
// EdgePool GNN pipeline.  N=100000, E=800000, F=128, H=64, G=8, C=10. f32.
// R1: two-stage k_gmp.  R2: dst-CSR gather.  R3: per-graph WG matching.
// R4: match state in LDS, streaming inline lists, ballot compaction.
// R5: XCD swizzle, epoch-tagged bcur, no-max softmax, merged partition.
// R6: pass fusion — k_transform2 computes both GEMMs in one x pass (u
//     aliases agg); k_gfin = gather+mean+relu+h-write+gmp in one kernel
//     (agg roundtrip + gmp h re-read gone); build_m/s merged (+cnt zero);
//     hash-table init folded into k_newx. ~36 -> ~23 dispatches.
// ---------------------------------------------------------------------------

// r = x@w_rel^T, u = x@w_root^T + bias  (both weights staged in LDS)
template <int K>
__global__ void k_transform2(const float* __restrict__ x, const float* __restrict__ wrel,
                             const float* __restrict__ wroot, const float* __restrict__ bias,
                             const int* __restrict__ nvP, float* __restrict__ r,
                             float* __restrict__ u, int n) {
  __shared__ float ws[64 * K];
  __shared__ float ws2[64 * K];
  for (int i = threadIdx.x; i < 64 * K; i += blockDim.x) { ws[i] = wrel[i]; ws2[i] = wroot[i]; }
  __syncthreads();
  int node = blockIdx.x * blockDim.x + threadIdx.x;
  if (node >= n) return;
  if (nvP && node >= *nvP) return;
  const float* xr = x + (size_t)node * K;
  float acc[64], acc2[64];
#pragma unroll
  for (int o = 0; o < 64; ++o) { acc[o] = 0.f; acc2[o] = bias[o]; }
  for (int k = 0; k < K; k += 4) {
    float4 xv = *reinterpret_cast<const float4*>(xr + k);
#pragma unroll
    for (int o = 0; o < 64; ++o) {
      float4 wv = *reinterpret_cast<const float4*>(&ws[o * K + k]);
      acc[o] = fmaf(xv.x, wv.x, acc[o]);
      acc[o] = fmaf(xv.y, wv.y, acc[o]);
      acc[o] = fmaf(xv.z, wv.z, acc[o]);
      acc[o] = fmaf(xv.w, wv.w, acc[o]);
      float4 w2 = *reinterpret_cast<const float4*>(&ws2[o * K + k]);
      acc2[o] = fmaf(xv.x, w2.x, acc2[o]);
      acc2[o] = fmaf(xv.y, w2.y, acc2[o]);
      acc2[o] = fmaf(xv.z, w2.z, acc2[o]);
      acc2[o] = fmaf(xv.w, w2.w, acc2[o]);
    }
  }
  float4* rr = reinterpret_cast<float4*>(r + (size_t)node * 64);
  float4* ur = reinterpret_cast<float4*>(u + (size_t)node * 64);
#pragma unroll
  for (int o = 0; o < 16; ++o) {
    rr[o] = make_float4(acc[4 * o], acc[4 * o + 1], acc[4 * o + 2], acc[4 * o + 3]);
    ur[o] = make_float4(acc2[4 * o], acc2[4 * o + 1], acc2[4 * o + 2], acc2[4 * o + 3]);
  }
}

// fused: dst-degree count + per-graph edge count (one pass over E)
__global__ void k_count(const int* __restrict__ dst, const int* __restrict__ src,
                        const int* __restrict__ batch, int* __restrict__ cnt,
                        int* __restrict__ gec, int e) {
  __shared__ int sc[8];
  if (threadIdx.x < 8) sc[threadIdx.x] = 0;
  __syncthreads();
  int i = blockIdx.x * blockDim.x + threadIdx.x;
  if (i < e) {
    atomicAdd(&cnt[dst[i]], 1);
    int g = batch[src[i]];
    if ((unsigned)g < 8u) atomicAdd(&sc[g], 1);
  }
  __syncthreads();
  if (threadIdx.x < 8 && sc[threadIdx.x]) atomicAdd(&gec[threadIdx.x], sc[threadIdx.x]);
}

// ---- 3-kernel exclusive scan over nc ints ----
__global__ void k_scan_sums(const int* __restrict__ in, int* __restrict__ bsum, int n) {
  __shared__ int sd[256];
  int base = blockIdx.x << 10;
  int s = 0;
  for (int j = threadIdx.x; j < 1024; j += 256) {
    int id = base + j;
    s += (id < n) ? in[id] : 0;
  }
  sd[threadIdx.x] = s;
  __syncthreads();
  for (int w = 128; w > 0; w >>= 1) {
    if (threadIdx.x < w) sd[threadIdx.x] += sd[threadIdx.x + w];
    __syncthreads();
  }
  if (threadIdx.x == 0) bsum[blockIdx.x] = sd[0];
}
__global__ void k_scan_tops(int* __restrict__ bsum, int nb, const int* __restrict__ gec,
                            int* __restrict__ gbase, int* __restrict__ gpos) {
  if (threadIdx.x == 0 && blockIdx.x == 0) {
    int acc = 0;
    for (int i = 0; i < nb; ++i) { int v = bsum[i]; bsum[i] = acc; acc += v; }
    if (gec) {
      int a2 = 0;
      for (int g = 0; g < 8; ++g) { gbase[g] = a2; gpos[g] = a2; a2 += gec[g]; }
      gbase[8] = a2;
    }
  }
}
__global__ void k_scan_out(const int* __restrict__ in, const int* __restrict__ bsum,
                           int* __restrict__ rowptr, int* __restrict__ pos, int n) {
  __shared__ int sd[256];
  int base = blockIdx.x << 10;
  int i0 = base + threadIdx.x * 4;
  int v0 = 0, v1 = 0, v2 = 0, v3 = 0;
  if (i0 < n) v0 = in[i0];
  if (i0 + 1 < n) v1 = in[i0 + 1];
  if (i0 + 2 < n) v2 = in[i0 + 2];
  if (i0 + 3 < n) v3 = in[i0 + 3];
  sd[threadIdx.x] = v0 + v1 + v2 + v3;
  __syncthreads();
  for (int off = 1; off < 256; off <<= 1) {
    int add = (threadIdx.x >= off) ? sd[threadIdx.x - off] : 0;
    __syncthreads();
    sd[threadIdx.x] += add;
    __syncthreads();
  }
  int excl = bsum[blockIdx.x] + (threadIdx.x ? sd[threadIdx.x - 1] : 0);
  if (i0 < n) { rowptr[i0] = excl; pos[i0] = excl; }
  excl += v0;
  if (i0 + 1 < n) { rowptr[i0 + 1] = excl; pos[i0 + 1] = excl; }
  excl += v1;
  if (i0 + 2 < n) { rowptr[i0 + 2] = excl; pos[i0 + 2] = excl; }
  excl += v2;
  if (i0 + 3 < n) { rowptr[i0 + 3] = excl; pos[i0 + 3] = excl; }
}

__global__ void k_fill(const int* __restrict__ src, const int* __restrict__ dst,
                       int* __restrict__ pos, int* __restrict__ col, int e, int n) {
  int i = blockIdx.x * blockDim.x + threadIdx.x;
  if (i >= e) return;
  int d = dst[i];
  if (d >= n) return;  // sentinel (pooled duplicates)
  int j = atomicAdd(&pos[d], 1);
  col[j] = src[i];
}

// R6 fused conv tail: CSR gather + mean + relu(s/deg + u) + h-write + gmp
// accumulation (+optional pool-score dots). Wave per node, contiguous node
// chunk per block; swz = XCD-affinity chunk permutation (conv1/2).
__global__ void k_gfin(const float* __restrict__ r, const float* __restrict__ u,
                       const int* __restrict__ rowptr, const int* __restrict__ col,
                       const int* __restrict__ batch, const int* __restrict__ gP,
                       const int* __restrict__ nvP, float* __restrict__ h,
                       const float* __restrict__ pw, float* __restrict__ aN,
                       float* __restrict__ bN, float* __restrict__ xs_sum,
                       float* __restrict__ gcnt, int count_nodes, int n, int swz) {
  __shared__ float sacc[8 * 64];
  __shared__ float scnt[8];
  __shared__ float pws[128];
  int G = *gP;
  int nv = nvP ? *nvP : n;
  if (nv > n) nv = n;
  for (int i = threadIdx.x; i < 8 * 64; i += blockDim.x) sacc[i] = 0.f;
  if (threadIdx.x < 8) scnt[threadIdx.x] = 0.f;
  if (pw) for (int i = threadIdx.x; i < 128; i += blockDim.x) pws[i] = pw[i];
  __syncthreads();
  int lane = threadIdx.x & 63, w = threadIdx.x >> 6;
  int nb = gridDim.x, b = blockIdx.x;
  if (swz) { int chunk = nb >> 3; b = (b & 7) * chunk + (b >> 3); }
  int cpb = (nv + nb - 1) / nb;
  int start = b * cpb;
  int end = start + cpb;
  if (end > nv) end = nv;
  for (int node = start + w; node < end; node += 4) {
    int bg = rowptr[node], e2 = rowptr[node + 1];
    float s = 0.f;
    for (int j = bg; j < e2; ++j) s += r[(size_t)col[j] * 64 + lane];
    int deg = e2 - bg;
    float inv = deg > 0 ? 1.f / (float)deg : 0.f;
    float v = fmaf(s, inv, u[(size_t)node * 64 + lane]);
    v = v > 0.f ? v : 0.f;
    h[(size_t)node * 64 + lane] = v;
    int g = batch[node];
    if ((unsigned)g < 8u && g < G) {
      atomicAdd(&sacc[g * 64 + lane], v);
      if (count_nodes && lane == 0) atomicAdd(&scnt[g], 1.f);
    }
    if (pw) {
      float d1 = v * pws[lane];
      float d2 = v * pws[64 + lane];
#pragma unroll
      for (int off = 32; off > 0; off >>= 1) {
        d1 += __shfl_down(d1, off, 64);
        d2 += __shfl_down(d2, off, 64);
      }
      if (lane == 0) { aN[node] = d1; bN[node] = d2; }
    }
  }
  __syncthreads();
  int lim = (G < 8 ? G : 8) * 64;
  for (int i = threadIdx.x; i < lim; i += blockDim.x) {
    float s = sacc[i];
    if (s != 0.f) atomicAdd(&xs_sum[i], s);
  }
  if (count_nodes && threadIdx.x < 8) {
    float c = scnt[threadIdx.x];
    if (c != 0.f) atomicAdd(&gcnt[threadIdx.x], c);
  }
}

// fused: raw score + exp + dst-grouped denominator (no max-sub; raw O(10))
__global__ void k_rawden(const float* __restrict__ aN, const float* __restrict__ bN,
                         const float* __restrict__ pbp, const int* __restrict__ src,
                         const int* __restrict__ dst, float* __restrict__ exs,
                         float* __restrict__ den, int e) {
  int i = blockIdx.x * blockDim.x + threadIdx.x;
  if (i >= e) return;
  int d = dst[i];
  float ex = expf(aN[src[i]] + bN[d] + pbp[0]);
  exs[i] = ex;
  atomicAdd(&den[d], ex);
}

// fused: score finalize + 52-bit key + per-graph partition fill.
__global__ void k_scorefill(float* __restrict__ exsc, const int* __restrict__ src,
                            const int* __restrict__ dst, const float* __restrict__ den,
                            const int* __restrict__ batch, const int* __restrict__ gP,
                            int* __restrict__ gpos, u64* __restrict__ keyA,
                            u32* __restrict__ sdA, int e, int N) {
  __shared__ int scnt[8], sbase[8];
  if (threadIdx.x < 8) scnt[threadIdx.x] = 0;
  __syncthreads();
  int i = blockIdx.x * blockDim.x + threadIdx.x;
  int g = -1, rank = 0, s = 0, d = 0;
  u64 k = 0;
  if (i < e) {
    s = src[i]; d = dst[i];
    float sc = exsc[i] / den[d] + 0.5f;
    exsc[i] = sc;
    k = ((u64)(u32)(~__float_as_uint(sc)) << 20) | (u32)i;
    g = batch[s];
    if ((unsigned)g < 8u) rank = atomicAdd(&scnt[g], 1);
    else g = -1;
  }
  __syncthreads();
  if (threadIdx.x < 8 && scnt[threadIdx.x])
    sbase[threadIdx.x] = atomicAdd(&gpos[threadIdx.x], scnt[threadIdx.x]);
  __syncthreads();
  if (g < 0) return;
  int per = N / *gP;
  int base = g * per;
  int j = sbase[g] + rank;
  keyA[j] = k;
  sdA[j] = ((u32)(s - base) << 16) | (u32)(d - base);
}

// Per-graph exact greedy matching (R4/R5): LDS state, epoch-tagged bcur.
#define PERMAX 12544
__global__ __launch_bounds__(1024) void k_match_wg(
    const int* __restrict__ gbase, const int* __restrict__ gP,
    u64* __restrict__ keyA, u64* __restrict__ keyB,
    u32* __restrict__ sdA, u32* __restrict__ sdB,
    int* __restrict__ dead, u8* __restrict__ matched, int N) {
  __shared__ u64 bcur[PERMAX];
  __shared__ u8 dead_s[PERMAX];
  __shared__ int lcnt;
  int G = *gP;
  int g = blockIdx.x;
  if (g >= G) return;
  int per = N / G;
  if (per > PERMAX) per = PERMAX;
  int base = g * per;
  int re = gbase[g];
  int n = gbase[g + 1] - re;
  int tid = threadIdx.x, lane = tid & 63;
  for (int i = tid; i < per; i += 1024) { bcur[i] = ~0ull; dead_s[i] = 0; }
  if (tid == 0) lcnt = 0;
  __syncthreads();
  u64* kin = keyA + re; u64* kout = keyB + re;
  u32* sin_ = sdA + re; u32* sout = sdB + re;
  for (int round = 0; n > 0 && round < 4000; ++round) {
    u64 etag = (u64)(4095 - round) << 52;
    for (int i = tid; i - lane < n; i += 1024) {
      bool inb = i < n;
      u32 sd = 0; u64 k = 0;
      if (inb) { sd = sin_[i]; k = kin[i]; }
      int s = sd >> 16, d = sd & 0xffff;
      bool alive = inb && !(dead_s[s] | dead_s[d]);
      if (alive) {
        u64 val = etag | k;
        atomicMin(&bcur[s], val);
        if (d != s) atomicMin(&bcur[d], val);
      }
      u64 m = __ballot(alive);
      if (m) {
        int lead = __ffsll((long long)m) - 1;
        int bse = 0;
        if (lane == lead) bse = atomicAdd(&lcnt, __popcll(m));
        bse = __shfl(bse, lead, 64);
        if (alive) {
          int j = bse + __popcll(m & ((1ull << lane) - 1ull));
          kout[j] = k;
          sout[j] = sd;
        }
      }
    }
    __syncthreads();
    int n2 = lcnt;
    if (n2 == 0) break;
    for (int i = tid; i < n2; i += 1024) {
      u32 sd = sout[i];
      u64 k = kout[i];
      int s = sd >> 16, d = sd & 0xffff;
      u64 val = etag | k;
      if (bcur[s] == val && (d == s || bcur[d] == val)) {
        matched[(u32)(k & 0xFFFFF)] = 1;
        dead_s[s] = 1;
        dead_s[d] = 1;
      }
    }
    if (tid == 0) lcnt = 0;
    __syncthreads();
    u64* tk = kin; kin = kout; kout = tk;
    u32* ts = sin_; sin_ = sout; sout = ts;
    n = n2;
  }
  __syncthreads();
  for (int i = tid; i < per; i += 1024) dead[base + i] = dead_s[i];
}

// merged: matched-pair clusters + singleton clusters + cnt zeroing.
__global__ void k_build_ms(const u8* __restrict__ matched, const int* __restrict__ src,
                           const int* __restrict__ dst, const int* __restrict__ batch,
                           const int* __restrict__ dead, int* __restrict__ cluster,
                           int* __restrict__ new_batch, int* __restrict__ srcE,
                           int* __restrict__ nclus, float* __restrict__ gccnt,
                           int* __restrict__ cnt, int e, int n, int nc) {
  __shared__ int sc[8];
  if (threadIdx.x < 8) sc[threadIdx.x] = 0;
  __syncthreads();
  int i = blockIdx.x * blockDim.x + threadIdx.x;
  if (i < nc) cnt[i] = 0;
  if (i < e && matched[i]) {
    int c = atomicAdd(nclus, 1);
    int s = src[i], d = dst[i];
    cluster[s] = c;
    cluster[d] = c;
    srcE[c] = i;
    int g = batch[s];
    new_batch[c] = g;
    if ((unsigned)g < 8u) atomicAdd(&sc[g], 1);
  }
  if (i < n && !dead[i]) {
    int c = atomicAdd(nclus, 1);
    cluster[i] = c;
    srcE[c] = ~i;  // singleton: encoded node
    int g = batch[i];
    new_batch[c] = g;
    if ((unsigned)g < 8u) atomicAdd(&sc[g], 1);
  }
  __syncthreads();
  if (threadIdx.x < 8 && sc[threadIdx.x] > 0)
    atomicAdd(&gccnt[threadIdx.x], (float)sc[threadIdx.x]);
}

#define HBITS 21
#define HMASK ((1u << HBITS) - 1u)

// cluster-driven new_x (wave per cluster) + hash-table init prologue.
__global__ void k_newx(const int* __restrict__ srcE, const int* __restrict__ src,
                       const int* __restrict__ dst, const float* __restrict__ score,
                       const int* __restrict__ nclusP, const float* __restrict__ h2,
                       float* __restrict__ new_x, u64* __restrict__ table, int n) {
  int idx = blockIdx.x * blockDim.x + threadIdx.x;
  if (idx < (1 << HBITS)) table[idx] = ~0ull;
  int c = idx >> 6;
  int lane = idx & 63;
  if (c >= n || c >= *nclusP) return;
  int v = srcE[c];
  float val;
  if (v >= 0) {
    int s = src[v], d = dst[v];
    val = h2[(size_t)s * 64 + lane];
    if (d != s) val += h2[(size_t)d * 64 + lane];
    val *= score[v];
  } else {
    val = h2[(size_t)(~v) * 64 + lane];
  }
  new_x[(size_t)c * 64 + lane] = val;
}

// coalesce(cluster[edge_index]): hash-dedup; dups -> sentinel n; counts kept.
__global__ void k_dedup(const int* __restrict__ src, const int* __restrict__ dst,
                        const int* __restrict__ cluster, u64* __restrict__ table,
                        int* __restrict__ ns, int* __restrict__ nd,
                        int* __restrict__ cnt, int e, int n) {
  int i = blockIdx.x * blockDim.x + threadIdx.x;
  if (i >= e) return;
  int cs_ = cluster[src[i]], cd_ = cluster[dst[i]];
  u64 kk = (u64)cs_ * (u64)(n + 1) + (u64)cd_;
  u32 pos = (u32)((kk * 0x9E3779B97F4A7C15ull) >> 43) & HMASK;
  while (true) {
    u64 old = atomicCAS(&table[pos], ~0ull, kk);
    if (old == ~0ull) {
      ns[i] = cs_; nd[i] = cd_;
      atomicAdd(&cnt[cd_], 1);
      return;
    }
    if (old == kk) { ns[i] = n; nd[i] = n; return; }
    pos = (pos + 1) & HMASK;
  }
}

// JK cat + lin1 + relu + lin2 + log_softmax. single block.
__global__ void k_head(const float* __restrict__ xs_sum /*4*8*64*/,
                       const float* __restrict__ gncnt, const float* __restrict__ gccnt,
                       const float* __restrict__ l1w, const float* __restrict__ l1b,
                       const float* __restrict__ l2w, const float* __restrict__ l2b,
                       const int* __restrict__ gP, float* __restrict__ out, int C) {
  __shared__ float z[8][256];
  __shared__ float z1[8][64];
  __shared__ float z2[8][16];
  int G = *gP;
  int tid = threadIdx.x;
  int p = tid >> 6, f = tid & 63;
  for (int g = 0; g < G; ++g) {
    float c = (p < 2) ? gncnt[g] : gccnt[g];
    if (c < 1.f) c = 1.f;
    z[g][tid] = xs_sum[(p * 8 + g) * 64 + f] / c;
  }
  __syncthreads();
  for (int idx = tid; idx < G * 64; idx += blockDim.x) {
    int g = idx >> 6, o = idx & 63;
    float a = l1b[o];
    for (int k = 0; k < 256; ++k) a = fmaf(z[g][k], l1w[o * 256 + k], a);
    z1[g][o] = a > 0.f ? a : 0.f;
  }
  __syncthreads();
  for (int idx = tid; idx < G * C; idx += blockDim.x) {
    int g = idx / C, c = idx % C;
    float a = l2b[c];
    for (int k = 0; k < 64; ++k) a = fmaf(z1[g][k], l2w[c * 64 + k], a);
    z2[g][c] = a;
  }
  __syncthreads();
  if (tid < G) {
    float m = z2[tid][0];
    for (int c = 1; c < C; ++c) m = fmaxf(m, z2[tid][c]);
    float s = 0.f;
    for (int c = 0; c < C; ++c) s += expf(z2[tid][c] - m);
    float lse = m + logf(s);
    for (int c = 0; c < C; ++c) out[tid * C + c] = z2[tid][c] - lse;
  }
}

extern "C" void kernel_launch(void* const* d_in, const int* in_sizes, int n_in,
                              void* d_out, int out_size, void* d_ws, size_t ws_size,
                              hipStream_t stream) {
  const float* x       = (const float*)d_in[0];
  const int*   ei      = (const int*)d_in[1];
  const int*   batch   = (const int*)d_in[2];
  const float* w_rel1  = (const float*)d_in[3];
  const float* b_rel1  = (const float*)d_in[4];
  const float* w_root1 = (const float*)d_in[5];
  const float* w_rel2  = (const float*)d_in[6];
  const float* b_rel2  = (const float*)d_in[7];
  const float* w_root2 = (const float*)d_in[8];
  const float* w_rel3  = (const float*)d_in[9];
  const float* b_rel3  = (const float*)d_in[10];
  const float* w_root3 = (const float*)d_in[11];
  const float* w_rel4  = (const float*)d_in[12];
  const float* b_rel4  = (const float*)d_in[13];
  const float* w_root4 = (const float*)d_in[14];
  const float* pool_w  = (const float*)d_in[15];
  const float* pool_b  = (const float*)d_in[16];
  const float* lin1_w  = (const float*)d_in[17];
  const float* lin1_b  = (const float*)d_in[18];
  const float* lin2_w  = (const float*)d_in[19];
  const float* lin2_b  = (const float*)d_in[20];
  const int*   gP      = (const int*)d_in[21];
  float* out = (float*)d_out;

  const int N = in_sizes[2];
  const int E = in_sizes[1] / 2;
  const int C = in_sizes[20];
  const int* src = ei;
  const int* dst = ei + E;

  // ---- workspace layout ----
  char* w = (char*)d_ws;
  auto alloc = [&](size_t bytes) -> char* {
    char* p = w;
    w += (bytes + 255) & ~(size_t)255;
    return p;
  };
  float* r      = (float*)alloc((size_t)N * 64 * 4);
  float* agg    = (float*)alloc((size_t)(N + 1) * 64 * 4);  // u / match lists / hash
  float* hA     = (float*)alloc((size_t)N * 64 * 4);        // h1 -> new_x -> h4
  float* hB     = (float*)alloc((size_t)N * 64 * 4);        // h2 -> h3
  float* score  = (float*)alloc((size_t)E * 4);             // ex -> score
  u64*   key    = (u64*)alloc((size_t)E * 8);               // ints alias: col
  int*   listA  = (int*)alloc((size_t)E * 4);               // aN -> ns
  int*   listB  = (int*)alloc((size_t)E * 4);               // bN -> nd
  int*   rowptr = (int*)alloc((size_t)(N + 2) * 4);
  int*   pos    = (int*)alloc((size_t)(N + 2) * 4);         // also srcE
  char* zstart = w;                                         // zeroed block
  int*   cnt       = (int*)alloc((size_t)(N + 2) * 4);
  int*   bsum      = (int*)alloc(1024);
  float* den       = (float*)alloc((size_t)N * 4);
  int*   dead      = (int*)alloc((size_t)N * 4);
  u8*    matched   = (u8*)alloc((size_t)E);
  int*   cluster   = (int*)alloc((size_t)N * 4);
  int*   new_batch = (int*)alloc((size_t)N * 4);
  float* small     = (float*)alloc(16384);
  size_t zbytes = (size_t)(w - zstart);
  if ((size_t)(w - (char*)d_ws) > ws_size) return;  // fail loudly

  int*   col = (int*)key;      // alias (col unused while matching)
  float* aN  = (float*)listA;  // alias: dots dead before ns/nd used
  float* bN  = (float*)listB;
  float* uB  = agg;            // u for all convs (agg phase-disjoint)
  u64*   keyA = (u64*)agg;     // match lists (after conv2 gfin, before build)
  u64*   keyB = keyA + E;
  u32*   sdA  = (u32*)(keyB + E);
  u32*   sdB  = sdA + E;
  u64*   table = (u64*)agg;    // hash (after match, before conv3)
  int*   srcE = pos;           // alias: pos re-filled later by 2nd scan_out

  float* xs_sum = small;                 // [4][8][64]
  float* gncnt  = small + 2048;          // [8]
  float* gccnt  = small + 2056;          // [8]
  int*   nclusP = (int*)(small + 2064);
  int*   gec    = (int*)(small + 2068);  // [8]
  int*   gbase  = (int*)(small + 2080);  // [9]
  int*   gpos   = (int*)(small + 2092);  // [8]

  const int TB = 256;
  const int gN = (N + TB - 1) / TB;
  const int gE = (E + TB - 1) / TB;
  const int gNw = (int)(((size_t)N * 64 + TB - 1) / TB);  // wave per item grids
  const int gFin = 1024;                                  // gfin grid (gmp-style flush)
  const int nc = N + 2;
  const int nb = (nc + 1023) / 1024;

  hipMemsetAsync(zstart, 0, zbytes, stream);

  // ---- CSR for original edges (+ per-graph edge counts) ----
  k_count<<<gE, TB, 0, stream>>>(dst, src, batch, cnt, gec, E);
  k_scan_sums<<<nb, TB, 0, stream>>>(cnt, bsum, nc);
  k_scan_tops<<<1, 64, 0, stream>>>(bsum, nb, gec, gbase, gpos);
  k_scan_out<<<nb, TB, 0, stream>>>(cnt, bsum, rowptr, pos, nc);
  k_fill<<<gE, TB, 0, stream>>>(src, dst, pos, col, E, N);

  // ---- conv1 (F=128 -> 64): dual-GEMM + fused gather/finish/gmp ----
  k_transform2<128><<<gN, TB, 0, stream>>>(x, w_rel1, w_root1, b_rel1, nullptr, r, uB, N);
  k_gfin<<<gFin, TB, 0, stream>>>(r, uB, rowptr, col, batch, gP, nullptr, hA,
                                  nullptr, nullptr, nullptr, xs_sum + 0 * 512, gncnt, 1, N, 1);

  // ---- conv2 (64 -> 64, + score dots) ----
  k_transform2<64><<<gN, TB, 0, stream>>>(hA, w_rel2, w_root2, b_rel2, nullptr, r, uB, N);
  k_gfin<<<gFin, TB, 0, stream>>>(r, uB, rowptr, col, batch, gP, nullptr, hB,
                                  pool_w, aN, bN, xs_sum + 1 * 512, nullptr, 0, N, 1);

  // ---- edge pooling: scores + per-graph partition ----
  k_rawden<<<gE, TB, 0, stream>>>(aN, bN, pool_b, src, dst, score, den, E);
  k_scorefill<<<gE, TB, 0, stream>>>(score, src, dst, den, batch, gP, gpos,
                                     keyA, sdA, E, N);

  // ---- greedy matching (per-graph workgroup, LDS state, epoch-tagged) ----
  k_match_wg<<<8, 1024, 0, stream>>>(gbase, gP, keyA, keyB, sdA, sdB, dead, matched, N);

  // ---- clusters (+cnt zero), new_x (+hash init), dedup ----
  k_build_ms<<<gE, TB, 0, stream>>>(matched, src, dst, batch, dead, cluster, new_batch,
                                    srcE, nclusP, gccnt, cnt, E, N, nc);
  k_newx<<<gNw, TB, 0, stream>>>(srcE, src, dst, score, nclusP, hB, hA, table, N);
  k_dedup<<<gE, TB, 0, stream>>>(src, dst, cluster, table, listA, listB, cnt, E, N);
  k_scan_sums<<<nb, TB, 0, stream>>>(cnt, bsum, nc);
  k_scan_tops<<<1, 64, 0, stream>>>(bsum, nb, nullptr, nullptr, nullptr);
  k_scan_out<<<nb, TB, 0, stream>>>(cnt, bsum, rowptr, pos, nc);
  k_fill<<<gE, TB, 0, stream>>>(listA, listB, pos, col, E, N);

  // ---- conv3 (64 -> 64, pooled) ----
  k_transform2<64><<<gN, TB, 0, stream>>>(hA, w_rel3, w_root3, b_rel3, nclusP, r, uB, N);
  k_gfin<<<gFin, TB, 0, stream>>>(r, uB, rowptr, col, new_batch, gP, nclusP, hB,
                                  nullptr, nullptr, nullptr, xs_sum + 2 * 512, nullptr, 0, N, 0);

  // ---- conv4 (64 -> 64, pooled) ----
  k_transform2<64><<<gN, TB, 0, stream>>>(hB, w_rel4, w_root4, b_rel4, nclusP, r, uB, N);
  k_gfin<<<gFin, TB, 0, stream>>>(r, uB, rowptr, col, new_batch, gP, nclusP, hA,
                                  nullptr, nullptr, nullptr, xs_sum + 3 * 512, nullptr, 0, N, 0);

  // ---- head ----
  k_head<<<1, TB, 0, stream>>>(xs_sum, gncnt, gccnt, lin1_w, lin1_b, lin2_w, lin2_b, gP, out, C);
}

// Round 8
// 1657.428 us; speedup vs baseline: 1.1925x; 1.1925x over previous
//
#include <hip/hip_runtime.h>
#include <stdint.h>

typedef unsigned long long u64;
typedef unsigned int u32;
typedef unsigned char u8;

// ---------------------------------------------------------------------------
// EdgePool GNN pipeline.  N=100000, E=800000, F=128, H=64, G=8, C=10. f32.
// R1: two-stage gmp.  R2: dst-CSR gather.  R3/R4: per-graph WG matching, LDS
// state.  R5: XCD swizzle, epoch bcur, no-max softmax.  R6: transform2 dual
// GEMM + gfin fusion (regressed: chunked grid lost parallelism).
// R7: wave-per-node gfin2 (parallelism restored, fusion kept) with gmp flush
//     to 64 partial buffers (same-address chains 3125->~390 @25ns/op);
//     two-phase k_build2 (512 chains); chunked scorefill/count (781 chains);
//     parallel scan_tops (was ~100-deep serial global RMW chain).
// ---------------------------------------------------------------------------

// r = x@w_rel^T, u = x@w_root^T + bias  (both weights staged in LDS)
template <int K>
__global__ void k_transform2(const float* __restrict__ x, const float* __restrict__ wrel,
                             const float* __restrict__ wroot, const float* __restrict__ bias,
                             const int* __restrict__ nvP, float* __restrict__ r,
                             float* __restrict__ u, int n) {
  __shared__ float ws[64 * K];
  __shared__ float ws2[64 * K];
  for (int i = threadIdx.x; i < 64 * K; i += blockDim.x) { ws[i] = wrel[i]; ws2[i] = wroot[i]; }
  __syncthreads();
  int node = blockIdx.x * blockDim.x + threadIdx.x;
  if (node >= n) return;
  if (nvP && node >= *nvP) return;
  const float* xr = x + (size_t)node * K;
  float acc[64], acc2[64];
#pragma unroll
  for (int o = 0; o < 64; ++o) { acc[o] = 0.f; acc2[o] = bias[o]; }
  for (int k = 0; k < K; k += 4) {
    float4 xv = *reinterpret_cast<const float4*>(xr + k);
#pragma unroll
    for (int o = 0; o < 64; ++o) {
      float4 wv = *reinterpret_cast<const float4*>(&ws[o * K + k]);
      acc[o] = fmaf(xv.x, wv.x, acc[o]);
      acc[o] = fmaf(xv.y, wv.y, acc[o]);
      acc[o] = fmaf(xv.z, wv.z, acc[o]);
      acc[o] = fmaf(xv.w, wv.w, acc[o]);
      float4 w2 = *reinterpret_cast<const float4*>(&ws2[o * K + k]);
      acc2[o] = fmaf(xv.x, w2.x, acc2[o]);
      acc2[o] = fmaf(xv.y, w2.y, acc2[o]);
      acc2[o] = fmaf(xv.z, w2.z, acc2[o]);
      acc2[o] = fmaf(xv.w, w2.w, acc2[o]);
    }
  }
  float4* rr = reinterpret_cast<float4*>(r + (size_t)node * 64);
  float4* ur = reinterpret_cast<float4*>(u + (size_t)node * 64);
#pragma unroll
  for (int o = 0; o < 16; ++o) {
    rr[o] = make_float4(acc[4 * o], acc[4 * o + 1], acc[4 * o + 2], acc[4 * o + 3]);
    ur[o] = make_float4(acc2[4 * o], acc2[4 * o + 1], acc2[4 * o + 2], acc2[4 * o + 3]);
  }
}

// dst-degree count + per-graph edge count; 1024-edge chunks (short flush chains)
__global__ void k_count(const int* __restrict__ dst, const int* __restrict__ src,
                        const int* __restrict__ batch, int* __restrict__ cnt,
                        int* __restrict__ gec, int e) {
  __shared__ int sc[8];
  if (threadIdx.x < 8) sc[threadIdx.x] = 0;
  __syncthreads();
  int base = blockIdx.x << 10;
#pragma unroll
  for (int k = 0; k < 4; ++k) {
    int i = base + k * 256 + threadIdx.x;
    if (i < e) {
      atomicAdd(&cnt[dst[i]], 1);
      int g = batch[src[i]];
      if ((unsigned)g < 8u) atomicAdd(&sc[g], 1);
    }
  }
  __syncthreads();
  if (threadIdx.x < 8 && sc[threadIdx.x]) atomicAdd(&gec[threadIdx.x], sc[threadIdx.x]);
}

// ---- scan over nc ints ----
__global__ void k_scan_sums(const int* __restrict__ in, int* __restrict__ bsum, int n) {
  __shared__ int sd[256];
  int base = blockIdx.x << 10;
  int s = 0;
  for (int j = threadIdx.x; j < 1024; j += 256) {
    int id = base + j;
    s += (id < n) ? in[id] : 0;
  }
  sd[threadIdx.x] = s;
  __syncthreads();
  for (int w = 128; w > 0; w >>= 1) {
    if (threadIdx.x < w) sd[threadIdx.x] += sd[threadIdx.x + w];
    __syncthreads();
  }
  if (threadIdx.x == 0) bsum[blockIdx.x] = sd[0];
}
// parallel LDS scan of block sums (nb <= 128); optional per-graph base scan
__global__ void k_scan_tops(int* __restrict__ bsum, int nb, const int* __restrict__ gec,
                            int* __restrict__ gbase, int* __restrict__ gpos) {
  __shared__ int sd[128];
  int tid = threadIdx.x;
  int v = (tid < nb) ? bsum[tid] : 0;
  sd[tid] = v;
  __syncthreads();
  for (int off = 1; off < 128; off <<= 1) {
    int add = (tid >= off) ? sd[tid - off] : 0;
    __syncthreads();
    sd[tid] += add;
    __syncthreads();
  }
  if (tid < nb) bsum[tid] = sd[tid] - v;  // exclusive
  if (gec && tid == 0) {
    int a2 = 0;
    for (int g = 0; g < 8; ++g) { gbase[g] = a2; gpos[g] = a2; a2 += gec[g]; }
    gbase[8] = a2;
  }
}
__global__ void k_scan_out(const int* __restrict__ in, const int* __restrict__ bsum,
                           int* __restrict__ rowptr, int* __restrict__ pos, int n) {
  __shared__ int sd[256];
  int base = blockIdx.x << 10;
  int i0 = base + threadIdx.x * 4;
  int v0 = 0, v1 = 0, v2 = 0, v3 = 0;
  if (i0 < n) v0 = in[i0];
  if (i0 + 1 < n) v1 = in[i0 + 1];
  if (i0 + 2 < n) v2 = in[i0 + 2];
  if (i0 + 3 < n) v3 = in[i0 + 3];
  sd[threadIdx.x] = v0 + v1 + v2 + v3;
  __syncthreads();
  for (int off = 1; off < 256; off <<= 1) {
    int add = (threadIdx.x >= off) ? sd[threadIdx.x - off] : 0;
    __syncthreads();
    sd[threadIdx.x] += add;
    __syncthreads();
  }
  int excl = bsum[blockIdx.x] + (threadIdx.x ? sd[threadIdx.x - 1] : 0);
  if (i0 < n) { rowptr[i0] = excl; pos[i0] = excl; }
  excl += v0;
  if (i0 + 1 < n) { rowptr[i0 + 1] = excl; pos[i0 + 1] = excl; }
  excl += v1;
  if (i0 + 2 < n) { rowptr[i0 + 2] = excl; pos[i0 + 2] = excl; }
  excl += v2;
  if (i0 + 3 < n) { rowptr[i0 + 3] = excl; pos[i0 + 3] = excl; }
}

__global__ void k_fill(const int* __restrict__ src, const int* __restrict__ dst,
                       int* __restrict__ pos, int* __restrict__ col, int e, int n) {
  int i = blockIdx.x * blockDim.x + threadIdx.x;
  if (i >= e) return;
  int d = dst[i];
  if (d >= n) return;  // sentinel (pooled duplicates)
  int j = atomicAdd(&pos[d], 1);
  col[j] = src[i];
}

// R7 fused conv tail: wave-per-node gather + mean + relu + h-write (+dots),
// gmp accumulated in LDS, flushed to 64 partial buffers (presence-masked).
__global__ void k_gfin2(const float* __restrict__ r, const float* __restrict__ u,
                        const int* __restrict__ rowptr, const int* __restrict__ col,
                        const int* __restrict__ batch, const int* __restrict__ gP,
                        const int* __restrict__ nvP, float* __restrict__ h,
                        const float* __restrict__ pw, float* __restrict__ aN,
                        float* __restrict__ bN, float* __restrict__ xs_part /*[64][512]*/,
                        float* __restrict__ gn_part /*[64][8] or null*/, int n, int swz) {
  __shared__ float sacc[512];
  __shared__ float scnt8[8];
  __shared__ float pws[128];
  __shared__ int pres;
  int G = *gP;
  int nv = nvP ? *nvP : n;
  if (nv > n) nv = n;
  for (int i = threadIdx.x; i < 512; i += 256) sacc[i] = 0.f;
  if (threadIdx.x < 8) scnt8[threadIdx.x] = 0.f;
  if (threadIdx.x == 0) pres = 0;
  if (pw && threadIdx.x < 128) pws[threadIdx.x] = pw[threadIdx.x];
  __syncthreads();
  int b = blockIdx.x;
  if (swz) { int chunk = gridDim.x >> 3; b = (b & 7) * chunk + (b >> 3); }
  int lane = threadIdx.x & 63, w = threadIdx.x >> 6;
  int node = b * 4 + w;
  if (node < nv) {
    int bg = rowptr[node], e2 = rowptr[node + 1];
    float s = 0.f;
    for (int j = bg; j < e2; ++j) s += r[(size_t)col[j] * 64 + lane];
    int deg = e2 - bg;
    float inv = deg > 0 ? 1.f / (float)deg : 0.f;
    float v = fmaf(s, inv, u[(size_t)node * 64 + lane]);
    v = v > 0.f ? v : 0.f;
    h[(size_t)node * 64 + lane] = v;
    if (pw) {
      float d1 = v * pws[lane];
      float d2 = v * pws[64 + lane];
#pragma unroll
      for (int off = 32; off > 0; off >>= 1) {
        d1 += __shfl_down(d1, off, 64);
        d2 += __shfl_down(d2, off, 64);
      }
      if (lane == 0) { aN[node] = d1; bN[node] = d2; }
    }
    int g = batch[node];
    if ((unsigned)g < 8u && g < G) {
      atomicAdd(&sacc[g * 64 + lane], v);
      if (lane == 0) {
        atomicOr(&pres, 1 << g);
        if (gn_part) atomicAdd(&scnt8[g], 1.f);
      }
    }
  }
  __syncthreads();
  int pm = pres;
  if (!pm) return;
  int buf = blockIdx.x & 63;
  float* xp = xs_part + buf * 512;
  for (int i = threadIdx.x; i < 512; i += 256) {
    if ((pm >> (i >> 6)) & 1) {
      float s2 = sacc[i];
      if (s2 != 0.f) atomicAdd(&xp[i], s2);
    }
  }
  if (gn_part && threadIdx.x < 8) {
    float c = scnt8[threadIdx.x];
    if (c != 0.f) atomicAdd(&gn_part[buf * 8 + threadIdx.x], c);
  }
}

// fused: raw score + exp + dst-grouped denominator (no max-sub; raw O(10))
__global__ void k_rawden(const float* __restrict__ aN, const float* __restrict__ bN,
                         const float* __restrict__ pbp, const int* __restrict__ src,
                         const int* __restrict__ dst, float* __restrict__ exs,
                         float* __restrict__ den, int e) {
  int i = blockIdx.x * blockDim.x + threadIdx.x;
  if (i >= e) return;
  int d = dst[i];
  float ex = expf(aN[src[i]] + bN[d] + pbp[0]);
  exs[i] = ex;
  atomicAdd(&den[d], ex);
}

// score finalize + 52-bit key + per-graph partition fill; 1024-edge chunks.
__global__ void k_scorefill(float* __restrict__ exsc, const int* __restrict__ src,
                            const int* __restrict__ dst, const float* __restrict__ den,
                            const int* __restrict__ batch, const int* __restrict__ gP,
                            int* __restrict__ gpos, u64* __restrict__ keyA,
                            u32* __restrict__ sdA, int e, int N) {
  __shared__ int scnt[8], sbase[8];
  if (threadIdx.x < 8) scnt[threadIdx.x] = 0;
  __syncthreads();
  int per = N / *gP;
  int base = blockIdx.x << 10;
  int gA[4], rkA[4], sA[4], dA[4];
  u64 kA[4];
#pragma unroll
  for (int k2 = 0; k2 < 4; ++k2) {
    int i = base + k2 * 256 + threadIdx.x;
    int g = -1;
    if (i < e) {
      int s = src[i], d = dst[i];
      float sc = exsc[i] / den[d] + 0.5f;
      exsc[i] = sc;
      g = batch[s];
      if ((unsigned)g < 8u) {
        rkA[k2] = atomicAdd(&scnt[g], 1);
        sA[k2] = s; dA[k2] = d;
        kA[k2] = ((u64)(u32)(~__float_as_uint(sc)) << 20) | (u32)i;
      } else g = -1;
    }
    gA[k2] = g;
  }
  __syncthreads();
  if (threadIdx.x < 8 && scnt[threadIdx.x])
    sbase[threadIdx.x] = atomicAdd(&gpos[threadIdx.x], scnt[threadIdx.x]);
  __syncthreads();
#pragma unroll
  for (int k2 = 0; k2 < 4; ++k2) {
    int g = gA[k2];
    if (g < 0) continue;
    int b2 = g * per;
    int j = sbase[g] + rkA[k2];
    keyA[j] = kA[k2];
    sdA[j] = ((u32)(sA[k2] - b2) << 16) | (u32)(dA[k2] - b2);
  }
}

// Per-graph exact greedy matching (R4/R5): LDS state, epoch-tagged bcur.
#define PERMAX 12544
__global__ __launch_bounds__(1024) void k_match_wg(
    const int* __restrict__ gbase, const int* __restrict__ gP,
    u64* __restrict__ keyA, u64* __restrict__ keyB,
    u32* __restrict__ sdA, u32* __restrict__ sdB,
    int* __restrict__ dead, u8* __restrict__ matched, int N) {
  __shared__ u64 bcur[PERMAX];
  __shared__ u8 dead_s[PERMAX];
  __shared__ int lcnt;
  int G = *gP;
  int g = blockIdx.x;
  if (g >= G) return;
  int per = N / G;
  if (per > PERMAX) per = PERMAX;
  int base = g * per;
  int re = gbase[g];
  int n = gbase[g + 1] - re;
  int tid = threadIdx.x, lane = tid & 63;
  for (int i = tid; i < per; i += 1024) { bcur[i] = ~0ull; dead_s[i] = 0; }
  if (tid == 0) lcnt = 0;
  __syncthreads();
  u64* kin = keyA + re; u64* kout = keyB + re;
  u32* sin_ = sdA + re; u32* sout = sdB + re;
  for (int round = 0; n > 0 && round < 4000; ++round) {
    u64 etag = (u64)(4095 - round) << 52;
    for (int i = tid; i - lane < n; i += 1024) {
      bool inb = i < n;
      u32 sd = 0; u64 k = 0;
      if (inb) { sd = sin_[i]; k = kin[i]; }
      int s = sd >> 16, d = sd & 0xffff;
      bool alive = inb && !(dead_s[s] | dead_s[d]);
      if (alive) {
        u64 val = etag | k;
        atomicMin(&bcur[s], val);
        if (d != s) atomicMin(&bcur[d], val);
      }
      u64 m = __ballot(alive);
      if (m) {
        int lead = __ffsll((long long)m) - 1;
        int bse = 0;
        if (lane == lead) bse = atomicAdd(&lcnt, __popcll(m));
        bse = __shfl(bse, lead, 64);
        if (alive) {
          int j = bse + __popcll(m & ((1ull << lane) - 1ull));
          kout[j] = k;
          sout[j] = sd;
        }
      }
    }
    __syncthreads();
    int n2 = lcnt;
    if (n2 == 0) break;
    for (int i = tid; i < n2; i += 1024) {
      u32 sd = sout[i];
      u64 k = kout[i];
      int s = sd >> 16, d = sd & 0xffff;
      u64 val = etag | k;
      if (bcur[s] == val && (d == s || bcur[d] == val)) {
        matched[(u32)(k & 0xFFFFF)] = 1;
        dead_s[s] = 1;
        dead_s[d] = 1;
      }
    }
    if (tid == 0) lcnt = 0;
    __syncthreads();
    u64* tk = kin; kin = kout; kout = tk;
    u32* ts = sin_; sin_ = sout; sout = ts;
    n = n2;
  }
  __syncthreads();
  for (int i = tid; i < per; i += 1024) dead[base + i] = dead_s[i];
}

// R7 two-phase cluster build (512 blocks): count -> one base atomic/block ->
// assign. Short same-address chains for nclus and gccnt. Also zeroes cnt.
__global__ void k_build2(const u8* __restrict__ matched, const int* __restrict__ src,
                         const int* __restrict__ dst, const int* __restrict__ batch,
                         const int* __restrict__ dead, int* __restrict__ cluster,
                         int* __restrict__ new_batch, int* __restrict__ srcE,
                         int* __restrict__ nclus, float* __restrict__ gccnt,
                         int* __restrict__ cnt, int e, int n, int nc) {
  __shared__ int c_cnt, c_off, basep;
  __shared__ int sc[8];
  if (threadIdx.x == 0) { c_cnt = 0; c_off = 0; basep = 0; }
  if (threadIdx.x < 8) sc[threadIdx.x] = 0;
  __syncthreads();
  int nbk = gridDim.x;
  for (int i = blockIdx.x * blockDim.x + threadIdx.x; i < nc; i += nbk * blockDim.x) cnt[i] = 0;
  int ec = (e + nbk - 1) / nbk, es = blockIdx.x * ec, ee = es + ec; if (ee > e) ee = e;
  int nk = (n + nbk - 1) / nbk, ns = blockIdx.x * nk, ne = ns + nk; if (ne > n) ne = n;
  int my = 0;
  for (int i = es + threadIdx.x; i < ee; i += blockDim.x) if (matched[i]) ++my;
  for (int i = ns + threadIdx.x; i < ne; i += blockDim.x) if (!dead[i]) ++my;
  if (my) atomicAdd(&c_cnt, my);
  __syncthreads();
  if (threadIdx.x == 0 && c_cnt) basep = atomicAdd(nclus, c_cnt);
  __syncthreads();
  int bse = basep;
  for (int i = es + threadIdx.x; i < ee; i += blockDim.x) {
    if (!matched[i]) continue;
    int c = bse + atomicAdd(&c_off, 1);
    int s = src[i], d = dst[i];
    cluster[s] = c;
    cluster[d] = c;
    srcE[c] = i;
    int g = batch[s];
    new_batch[c] = g;
    if ((unsigned)g < 8u) atomicAdd(&sc[g], 1);
  }
  for (int i = ns + threadIdx.x; i < ne; i += blockDim.x) {
    if (dead[i]) continue;
    int c = bse + atomicAdd(&c_off, 1);
    cluster[i] = c;
    srcE[c] = ~i;  // singleton: encoded node
    int g = batch[i];
    new_batch[c] = g;
    if ((unsigned)g < 8u) atomicAdd(&sc[g], 1);
  }
  __syncthreads();
  if (threadIdx.x < 8 && sc[threadIdx.x] > 0)
    atomicAdd(&gccnt[threadIdx.x], (float)sc[threadIdx.x]);
}

#define HBITS 21
#define HMASK ((1u << HBITS) - 1u)

// cluster-driven new_x (wave per cluster) + hash-table init prologue.
__global__ void k_newx(const int* __restrict__ srcE, const int* __restrict__ src,
                       const int* __restrict__ dst, const float* __restrict__ score,
                       const int* __restrict__ nclusP, const float* __restrict__ h2,
                       float* __restrict__ new_x, u64* __restrict__ table, int n) {
  int idx = blockIdx.x * blockDim.x + threadIdx.x;
  if (idx < (1 << HBITS)) table[idx] = ~0ull;
  int c = idx >> 6;
  int lane = idx & 63;
  if (c >= n || c >= *nclusP) return;
  int v = srcE[c];
  float val;
  if (v >= 0) {
    int s = src[v], d = dst[v];
    val = h2[(size_t)s * 64 + lane];
    if (d != s) val += h2[(size_t)d * 64 + lane];
    val *= score[v];
  } else {
    val = h2[(size_t)(~v) * 64 + lane];
  }
  new_x[(size_t)c * 64 + lane] = val;
}

// coalesce(cluster[edge_index]): hash-dedup; dups -> sentinel n; counts kept.
__global__ void k_dedup(const int* __restrict__ src, const int* __restrict__ dst,
                        const int* __restrict__ cluster, u64* __restrict__ table,
                        int* __restrict__ ns, int* __restrict__ nd,
                        int* __restrict__ cnt, int e, int n) {
  int i = blockIdx.x * blockDim.x + threadIdx.x;
  if (i >= e) return;
  int cs_ = cluster[src[i]], cd_ = cluster[dst[i]];
  u64 kk = (u64)cs_ * (u64)(n + 1) + (u64)cd_;
  u32 pos = (u32)((kk * 0x9E3779B97F4A7C15ull) >> 43) & HMASK;
  while (true) {
    u64 old = atomicCAS(&table[pos], ~0ull, kk);
    if (old == ~0ull) {
      ns[i] = cs_; nd[i] = cd_;
      atomicAdd(&cnt[cd_], 1);
      return;
    }
    if (old == kk) { ns[i] = n; nd[i] = n; return; }
    pos = (pos + 1) & HMASK;
  }
}

// JK cat (partial-buffer reduce) + lin1 + relu + lin2 + log_softmax.
__global__ void k_head(const float* __restrict__ xs_part /*[4][64][512]*/,
                       const float* __restrict__ gn_part /*[64][8]*/,
                       const float* __restrict__ gccnt,
                       const float* __restrict__ l1w, const float* __restrict__ l1b,
                       const float* __restrict__ l2w, const float* __restrict__ l2b,
                       const int* __restrict__ gP, float* __restrict__ out, int C) {
  __shared__ float z[8][256];
  __shared__ float z1[8][64];
  __shared__ float z2[8][16];
  __shared__ float gnc[8];
  int G = *gP;
  int tid = threadIdx.x;
  if (tid < 8) {
    float s = 0.f;
    for (int b = 0; b < 64; ++b) s += gn_part[b * 8 + tid];
    gnc[tid] = s;
  }
  __syncthreads();
  int p = tid >> 6, f = tid & 63;
  for (int g = 0; g < G; ++g) {
    const float* xp = xs_part + (size_t)p * 64 * 512;
    float s = 0.f;
    for (int b = 0; b < 64; ++b) s += xp[b * 512 + g * 64 + f];
    float c = (p < 2) ? gnc[g] : gccnt[g];
    if (c < 1.f) c = 1.f;
    z[g][tid] = s / c;
  }
  __syncthreads();
  for (int idx = tid; idx < G * 64; idx += blockDim.x) {
    int g = idx >> 6, o = idx & 63;
    float a = l1b[o];
    for (int k = 0; k < 256; ++k) a = fmaf(z[g][k], l1w[o * 256 + k], a);
    z1[g][o] = a > 0.f ? a : 0.f;
  }
  __syncthreads();
  for (int idx = tid; idx < G * C; idx += blockDim.x) {
    int g = idx / C, c = idx % C;
    float a = l2b[c];
    for (int k = 0; k < 64; ++k) a = fmaf(z1[g][k], l2w[c * 64 + k], a);
    z2[g][c] = a;
  }
  __syncthreads();
  if (tid < G) {
    float m = z2[tid][0];
    for (int c = 1; c < C; ++c) m = fmaxf(m, z2[tid][c]);
    float s = 0.f;
    for (int c = 0; c < C; ++c) s += expf(z2[tid][c] - m);
    float lse = m + logf(s);
    for (int c = 0; c < C; ++c) out[tid * C + c] = z2[tid][c] - lse;
  }
}

extern "C" void kernel_launch(void* const* d_in, const int* in_sizes, int n_in,
                              void* d_out, int out_size, void* d_ws, size_t ws_size,
                              hipStream_t stream) {
  const float* x       = (const float*)d_in[0];
  const int*   ei      = (const int*)d_in[1];
  const int*   batch   = (const int*)d_in[2];
  const float* w_rel1  = (const float*)d_in[3];
  const float* b_rel1  = (const float*)d_in[4];
  const float* w_root1 = (const float*)d_in[5];
  const float* w_rel2  = (const float*)d_in[6];
  const float* b_rel2  = (const float*)d_in[7];
  const float* w_root2 = (const float*)d_in[8];
  const float* w_rel3  = (const float*)d_in[9];
  const float* b_rel3  = (const float*)d_in[10];
  const float* w_root3 = (const float*)d_in[11];
  const float* w_rel4  = (const float*)d_in[12];
  const float* b_rel4  = (const float*)d_in[13];
  const float* w_root4 = (const float*)d_in[14];
  const float* pool_w  = (const float*)d_in[15];
  const float* pool_b  = (const float*)d_in[16];
  const float* lin1_w  = (const float*)d_in[17];
  const float* lin1_b  = (const float*)d_in[18];
  const float* lin2_w  = (const float*)d_in[19];
  const float* lin2_b  = (const float*)d_in[20];
  const int*   gP      = (const int*)d_in[21];
  float* out = (float*)d_out;

  const int N = in_sizes[2];
  const int E = in_sizes[1] / 2;
  const int C = in_sizes[20];
  const int* src = ei;
  const int* dst = ei + E;

  // ---- workspace layout ----
  char* w = (char*)d_ws;
  auto alloc = [&](size_t bytes) -> char* {
    char* p = w;
    w += (bytes + 255) & ~(size_t)255;
    return p;
  };
  float* r      = (float*)alloc((size_t)N * 64 * 4);
  float* agg    = (float*)alloc((size_t)(N + 1) * 64 * 4);  // u / match lists / hash
  float* hA     = (float*)alloc((size_t)N * 64 * 4);        // h1 -> new_x -> h4
  float* hB     = (float*)alloc((size_t)N * 64 * 4);        // h2 -> h3
  float* score  = (float*)alloc((size_t)E * 4);             // ex -> score
  u64*   key    = (u64*)alloc((size_t)E * 8);               // ints alias: col
  int*   listA  = (int*)alloc((size_t)E * 4);               // aN -> ns
  int*   listB  = (int*)alloc((size_t)E * 4);               // bN -> nd
  int*   rowptr = (int*)alloc((size_t)(N + 2) * 4);
  int*   pos    = (int*)alloc((size_t)(N + 2) * 4);         // also srcE
  char* zstart = w;                                         // zeroed block
  int*   cnt       = (int*)alloc((size_t)(N + 2) * 4);
  int*   bsum      = (int*)alloc(1024);
  float* den       = (float*)alloc((size_t)N * 4);
  int*   dead      = (int*)alloc((size_t)N * 4);
  u8*    matched   = (u8*)alloc((size_t)E);
  int*   cluster   = (int*)alloc((size_t)N * 4);
  int*   new_batch = (int*)alloc((size_t)N * 4);
  float* xs_part   = (float*)alloc((size_t)4 * 64 * 512 * 4);  // per-stage partials
  float* gn_part   = (float*)alloc((size_t)64 * 8 * 4);
  float* small     = (float*)alloc(16384);
  size_t zbytes = (size_t)(w - zstart);
  if ((size_t)(w - (char*)d_ws) > ws_size) return;  // fail loudly

  int*   col = (int*)key;      // alias (col unused while matching)
  float* aN  = (float*)listA;  // alias: dots dead before ns/nd used
  float* bN  = (float*)listB;
  float* uB  = agg;            // u for all convs (agg phase-disjoint)
  u64*   keyA = (u64*)agg;     // match lists (after conv2 gfin, before build)
  u64*   keyB = keyA + E;
  u32*   sdA  = (u32*)(keyB + E);
  u32*   sdB  = sdA + E;
  u64*   table = (u64*)agg;    // hash (after match, before conv3)
  int*   srcE = pos;           // alias: pos re-filled later by 2nd scan_out

  float* gccnt  = small;                 // [8]
  int*   nclusP = (int*)(small + 16);
  int*   gec    = (int*)(small + 20);    // [8]
  int*   gbase  = (int*)(small + 32);    // [9]
  int*   gpos   = (int*)(small + 44);    // [8]

  const int TB = 256;
  const int gN = (N + TB - 1) / TB;
  const int gE = (E + TB - 1) / TB;
  const int gE1k = (E + 1023) >> 10;                      // 1024-edge chunks
  const int gNw = (int)(((size_t)N * 64 + TB - 1) / TB);  // wave per node
  const int swz = (gNw % 8 == 0) ? 1 : 0;
  const int nc = N + 2;
  const int nb = (nc + 1023) / 1024;

  hipMemsetAsync(zstart, 0, zbytes, stream);

  // ---- CSR for original edges (+ per-graph edge counts) ----
  k_count<<<gE1k, TB, 0, stream>>>(dst, src, batch, cnt, gec, E);
  k_scan_sums<<<nb, TB, 0, stream>>>(cnt, bsum, nc);
  k_scan_tops<<<1, 128, 0, stream>>>(bsum, nb, gec, gbase, gpos);
  k_scan_out<<<nb, TB, 0, stream>>>(cnt, bsum, rowptr, pos, nc);
  k_fill<<<gE, TB, 0, stream>>>(src, dst, pos, col, E, N);

  // ---- conv1 (F=128 -> 64) ----
  k_transform2<128><<<gN, TB, 0, stream>>>(x, w_rel1, w_root1, b_rel1, nullptr, r, uB, N);
  k_gfin2<<<gNw, TB, 0, stream>>>(r, uB, rowptr, col, batch, gP, nullptr, hA,
                                  nullptr, nullptr, nullptr, xs_part + 0 * 32768, gn_part, N, swz);

  // ---- conv2 (64 -> 64, + score dots) ----
  k_transform2<64><<<gN, TB, 0, stream>>>(hA, w_rel2, w_root2, b_rel2, nullptr, r, uB, N);
  k_gfin2<<<gNw, TB, 0, stream>>>(r, uB, rowptr, col, batch, gP, nullptr, hB,
                                  pool_w, aN, bN, xs_part + 1 * 32768, nullptr, N, swz);

  // ---- edge pooling: scores + per-graph partition ----
  k_rawden<<<gE, TB, 0, stream>>>(aN, bN, pool_b, src, dst, score, den, E);
  k_scorefill<<<gE1k, TB, 0, stream>>>(score, src, dst, den, batch, gP, gpos,
                                       keyA, sdA, E, N);

  // ---- greedy matching (per-graph workgroup, LDS state, epoch-tagged) ----
  k_match_wg<<<8, 1024, 0, stream>>>(gbase, gP, keyA, keyB, sdA, sdB, dead, matched, N);

  // ---- clusters (two-phase), new_x (+hash init), dedup + pooled CSR ----
  k_build2<<<512, TB, 0, stream>>>(matched, src, dst, batch, dead, cluster, new_batch,
                                   srcE, nclusP, gccnt, cnt, E, N, nc);
  k_newx<<<gNw, TB, 0, stream>>>(srcE, src, dst, score, nclusP, hB, hA, table, N);
  k_dedup<<<gE, TB, 0, stream>>>(src, dst, cluster, table, listA, listB, cnt, E, N);
  k_scan_sums<<<nb, TB, 0, stream>>>(cnt, bsum, nc);
  k_scan_tops<<<1, 128, 0, stream>>>(bsum, nb, nullptr, nullptr, nullptr);
  k_scan_out<<<nb, TB, 0, stream>>>(cnt, bsum, rowptr, pos, nc);
  k_fill<<<gE, TB, 0, stream>>>(listA, listB, pos, col, E, N);

  // ---- conv3 (64 -> 64, pooled) ----
  k_transform2<64><<<gN, TB, 0, stream>>>(hA, w_rel3, w_root3, b_rel3, nclusP, r, uB, N);
  k_gfin2<<<gNw, TB, 0, stream>>>(r, uB, rowptr, col, new_batch, gP, nclusP, hB,
                                  nullptr, nullptr, nullptr, xs_part + 2 * 32768, nullptr, N, 0);

  // ---- conv4 (64 -> 64, pooled) ----
  k_transform2<64><<<gN, TB, 0, stream>>>(hB, w_rel4, w_root4, b_rel4, nclusP, r, uB, N);
  k_gfin2<<<gNw, TB, 0, stream>>>(r, uB, rowptr, col, new_batch, gP, nclusP, hA,
                                  nullptr, nullptr, nullptr, xs_part + 3 * 32768, nullptr, N, 0);

  // ---- head ----
  k_head<<<1, TB, 0, stream>>>(xs_part, gn_part, gccnt, lin1_w, lin1_b, lin2_w, lin2_b, gP, out, C);
}

// Round 9
// 1649.617 us; speedup vs baseline: 1.1981x; 1.0047x over previous
//
#include <hip/hip_runtime.h>
#include <stdint.h>

typedef unsigned long long u64;
typedef unsigned int u32;
typedef unsigned char u8;

// ---------------------------------------------------------------------------
// EdgePool GNN pipeline.  N=100000, E=800000, F=128, H=64, G=8, C=10. f32.
// R1 two-stage gmp · R2 dst-CSR gather · R3/R4 per-graph WG match in LDS ·
// R5 XCD swizzle + epoch bcur + no-max softmax · R7 wave-per-node gfin2,
// partial-buffer gmp flush, two-phase build, parallel scan_tops.
// R8: (a) k_match_wg LDS tail mode — alive list <=3072 lives entirely in
//     LDS, no compaction, rounds at LDS latency (was: every round ping-pongs
//     global lists; 278us was round-latency bound, VALUBusy 1%);
//     read-before-atomicMin cuts LDS conflict cycles. (b) CSR-ordered
//     scoring: dst-CSR order is per-graph contiguous, so gbase=rowptr[g*per]
//     and rawden+scorefill collapse into one thread-per-dst kernel (no den
//     array, no partition ranking, no E-atomics).
// ---------------------------------------------------------------------------

// r = x@w_rel^T, u = x@w_root^T + bias  (both weights staged in LDS)
template <int K>
__global__ void k_transform2(const float* __restrict__ x, const float* __restrict__ wrel,
                             const float* __restrict__ wroot, const float* __restrict__ bias,
                             const int* __restrict__ nvP, float* __restrict__ r,
                             float* __restrict__ u, int n) {
  __shared__ float ws[64 * K];
  __shared__ float ws2[64 * K];
  for (int i = threadIdx.x; i < 64 * K; i += blockDim.x) { ws[i] = wrel[i]; ws2[i] = wroot[i]; }
  __syncthreads();
  int node = blockIdx.x * blockDim.x + threadIdx.x;
  if (node >= n) return;
  if (nvP && node >= *nvP) return;
  const float* xr = x + (size_t)node * K;
  float acc[64], acc2[64];
#pragma unroll
  for (int o = 0; o < 64; ++o) { acc[o] = 0.f; acc2[o] = bias[o]; }
  for (int k = 0; k < K; k += 4) {
    float4 xv = *reinterpret_cast<const float4*>(xr + k);
#pragma unroll
    for (int o = 0; o < 64; ++o) {
      float4 wv = *reinterpret_cast<const float4*>(&ws[o * K + k]);
      acc[o] = fmaf(xv.x, wv.x, acc[o]);
      acc[o] = fmaf(xv.y, wv.y, acc[o]);
      acc[o] = fmaf(xv.z, wv.z, acc[o]);
      acc[o] = fmaf(xv.w, wv.w, acc[o]);
      float4 w2 = *reinterpret_cast<const float4*>(&ws2[o * K + k]);
      acc2[o] = fmaf(xv.x, w2.x, acc2[o]);
      acc2[o] = fmaf(xv.y, w2.y, acc2[o]);
      acc2[o] = fmaf(xv.z, w2.z, acc2[o]);
      acc2[o] = fmaf(xv.w, w2.w, acc2[o]);
    }
  }
  float4* rr = reinterpret_cast<float4*>(r + (size_t)node * 64);
  float4* ur = reinterpret_cast<float4*>(u + (size_t)node * 64);
#pragma unroll
  for (int o = 0; o < 16; ++o) {
    rr[o] = make_float4(acc[4 * o], acc[4 * o + 1], acc[4 * o + 2], acc[4 * o + 3]);
    ur[o] = make_float4(acc2[4 * o], acc2[4 * o + 1], acc2[4 * o + 2], acc2[4 * o + 3]);
  }
}

// dst-degree count; 1024-edge chunks
__global__ void k_count(const int* __restrict__ dst, int* __restrict__ cnt, int e) {
  int base = blockIdx.x << 10;
#pragma unroll
  for (int k = 0; k < 4; ++k) {
    int i = base + k * 256 + threadIdx.x;
    if (i < e) atomicAdd(&cnt[dst[i]], 1);
  }
}

// ---- scan over nc ints ----
__global__ void k_scan_sums(const int* __restrict__ in, int* __restrict__ bsum, int n) {
  __shared__ int sd[256];
  int base = blockIdx.x << 10;
  int s = 0;
  for (int j = threadIdx.x; j < 1024; j += 256) {
    int id = base + j;
    s += (id < n) ? in[id] : 0;
  }
  sd[threadIdx.x] = s;
  __syncthreads();
  for (int w = 128; w > 0; w >>= 1) {
    if (threadIdx.x < w) sd[threadIdx.x] += sd[threadIdx.x + w];
    __syncthreads();
  }
  if (threadIdx.x == 0) bsum[blockIdx.x] = sd[0];
}
__global__ void k_scan_tops(int* __restrict__ bsum, int nb) {
  __shared__ int sd[128];
  int tid = threadIdx.x;
  int v = (tid < nb) ? bsum[tid] : 0;
  sd[tid] = v;
  __syncthreads();
  for (int off = 1; off < 128; off <<= 1) {
    int add = (tid >= off) ? sd[tid - off] : 0;
    __syncthreads();
    sd[tid] += add;
    __syncthreads();
  }
  if (tid < nb) bsum[tid] = sd[tid] - v;  // exclusive
}
__global__ void k_scan_out(const int* __restrict__ in, const int* __restrict__ bsum,
                           int* __restrict__ rowptr, int* __restrict__ pos, int n) {
  __shared__ int sd[256];
  int base = blockIdx.x << 10;
  int i0 = base + threadIdx.x * 4;
  int v0 = 0, v1 = 0, v2 = 0, v3 = 0;
  if (i0 < n) v0 = in[i0];
  if (i0 + 1 < n) v1 = in[i0 + 1];
  if (i0 + 2 < n) v2 = in[i0 + 2];
  if (i0 + 3 < n) v3 = in[i0 + 3];
  sd[threadIdx.x] = v0 + v1 + v2 + v3;
  __syncthreads();
  for (int off = 1; off < 256; off <<= 1) {
    int add = (threadIdx.x >= off) ? sd[threadIdx.x - off] : 0;
    __syncthreads();
    sd[threadIdx.x] += add;
    __syncthreads();
  }
  int excl = bsum[blockIdx.x] + (threadIdx.x ? sd[threadIdx.x - 1] : 0);
  if (i0 < n) { rowptr[i0] = excl; pos[i0] = excl; }
  excl += v0;
  if (i0 + 1 < n) { rowptr[i0 + 1] = excl; pos[i0 + 1] = excl; }
  excl += v1;
  if (i0 + 2 < n) { rowptr[i0 + 2] = excl; pos[i0 + 2] = excl; }
  excl += v2;
  if (i0 + 3 < n) { rowptr[i0 + 3] = excl; pos[i0 + 3] = excl; }
}

// CSR fill: col = src, eid = original edge index
__global__ void k_fill(const int* __restrict__ src, const int* __restrict__ dst,
                       int* __restrict__ pos, int* __restrict__ col,
                       int* __restrict__ eid, int e, int n) {
  int i = blockIdx.x * blockDim.x + threadIdx.x;
  if (i >= e) return;
  int d = dst[i];
  if (d >= n) return;  // sentinel (pooled duplicates)
  int j = atomicAdd(&pos[d], 1);
  col[j] = src[i];
  if (eid) eid[j] = i;
}

// R7 fused conv tail: wave-per-node gather + mean + relu + h-write (+dots),
// gmp accumulated in LDS, flushed to 64 partial buffers (presence-masked).
__global__ void k_gfin2(const float* __restrict__ r, const float* __restrict__ u,
                        const int* __restrict__ rowptr, const int* __restrict__ col,
                        const int* __restrict__ batch, const int* __restrict__ gP,
                        const int* __restrict__ nvP, float* __restrict__ h,
                        const float* __restrict__ pw, float* __restrict__ aN,
                        float* __restrict__ bN, float* __restrict__ xs_part /*[64][512]*/,
                        float* __restrict__ gn_part /*[64][8] or null*/, int n, int swz) {
  __shared__ float sacc[512];
  __shared__ float scnt8[8];
  __shared__ float pws[128];
  __shared__ int pres;
  int G = *gP;
  int nv = nvP ? *nvP : n;
  if (nv > n) nv = n;
  for (int i = threadIdx.x; i < 512; i += 256) sacc[i] = 0.f;
  if (threadIdx.x < 8) scnt8[threadIdx.x] = 0.f;
  if (threadIdx.x == 0) pres = 0;
  if (pw && threadIdx.x < 128) pws[threadIdx.x] = pw[threadIdx.x];
  __syncthreads();
  int b = blockIdx.x;
  if (swz) { int chunk = gridDim.x >> 3; b = (b & 7) * chunk + (b >> 3); }
  int lane = threadIdx.x & 63, w = threadIdx.x >> 6;
  int node = b * 4 + w;
  if (node < nv) {
    int bg = rowptr[node], e2 = rowptr[node + 1];
    float s = 0.f;
    for (int j = bg; j < e2; ++j) s += r[(size_t)col[j] * 64 + lane];
    int deg = e2 - bg;
    float inv = deg > 0 ? 1.f / (float)deg : 0.f;
    float v = fmaf(s, inv, u[(size_t)node * 64 + lane]);
    v = v > 0.f ? v : 0.f;
    h[(size_t)node * 64 + lane] = v;
    if (pw) {
      float d1 = v * pws[lane];
      float d2 = v * pws[64 + lane];
#pragma unroll
      for (int off = 32; off > 0; off >>= 1) {
        d1 += __shfl_down(d1, off, 64);
        d2 += __shfl_down(d2, off, 64);
      }
      if (lane == 0) { aN[node] = d1; bN[node] = d2; }
    }
    int g = batch[node];
    if ((unsigned)g < 8u && g < G) {
      atomicAdd(&sacc[g * 64 + lane], v);
      if (lane == 0) {
        atomicOr(&pres, 1 << g);
        if (gn_part) atomicAdd(&scnt8[g], 1.f);
      }
    }
  }
  __syncthreads();
  int pm = pres;
  if (!pm) return;
  int buf = blockIdx.x & 63;
  float* xp = xs_part + buf * 512;
  for (int i = threadIdx.x; i < 512; i += 256) {
    if ((pm >> (i >> 6)) & 1) {
      float s2 = sacc[i];
      if (s2 != 0.f) atomicAdd(&xp[i], s2);
    }
  }
  if (gn_part && threadIdx.x < 8) {
    float c = scnt8[threadIdx.x];
    if (c != 0.f) atomicAdd(&gn_part[buf * 8 + threadIdx.x], c);
  }
}

// R8: CSR-ordered scoring. Thread per dst node: softmax over its in-edges,
// score -> original-edge slot, (key,sd) -> CSR slot (per-graph contiguous).
__global__ void k_score_csr(const float* __restrict__ aN, const float* __restrict__ bN,
                            const float* __restrict__ pbp, const int* __restrict__ rowptr,
                            const int* __restrict__ col, const int* __restrict__ eid,
                            const int* __restrict__ gP, float* __restrict__ score,
                            u64* __restrict__ keyA, u32* __restrict__ sdA, int N) {
  int d = blockIdx.x * blockDim.x + threadIdx.x;
  if (d >= N) return;
  int b = rowptr[d], e2 = rowptr[d + 1];
  if (b == e2) return;
  float bd = bN[d] + pbp[0];
  float den = 0.f;
  for (int j = b; j < e2; ++j) den += expf(aN[col[j]] + bd);
  int per = N / *gP;
  int g = d / per;
  int base = g * per;
  u32 dl = (u32)(d - base);
  for (int j = b; j < e2; ++j) {
    int s = col[j];
    int ei = eid[j];
    float sc = expf(aN[s] + bd) / den + 0.5f;
    score[ei] = sc;
    keyA[j] = ((u64)(u32)(~__float_as_uint(sc)) << 20) | (u32)ei;
    sdA[j] = ((u32)(s - base) << 16) | dl;
  }
}

// Per-graph exact greedy matching. R8: global rounds with compaction +
// LDS shadow copy; once alive <=TAILCAP the whole list lives in LDS and
// rounds run at LDS latency (no compaction — bcur equality test decides;
// epoch tags make stale entries inert). Read-before-atomicMin throughout.
#define PERMAX 12544
#define TAILCAP 3072
__global__ __launch_bounds__(1024) void k_match_wg(
    const int* __restrict__ rowptr, const int* __restrict__ gP,
    u64* __restrict__ keyA, u64* __restrict__ keyB,
    u32* __restrict__ sdA, u32* __restrict__ sdB,
    int* __restrict__ dead, u8* __restrict__ matched, int N) {
  __shared__ u64 bcur[PERMAX];
  __shared__ u8 dead_s[PERMAX];
  __shared__ u64 tkey[TAILCAP];
  __shared__ u32 tsd[TAILCAP];
  __shared__ int lcnt;
  int G = *gP;
  int g = blockIdx.x;
  if (g >= G) return;
  int per = N / G;
  if (per > PERMAX) per = PERMAX;
  int base = g * per;
  int re = rowptr[base];
  int n = rowptr[base + per] - re;  // dst-CSR rows are per-graph contiguous
  int tid = threadIdx.x, lane = tid & 63;
  for (int i = tid; i < per; i += 1024) { bcur[i] = ~0ull; dead_s[i] = 0; }
  if (tid == 0) lcnt = 0;
  __syncthreads();
  u64* kin = keyA + re; u64* kout = keyB + re;
  u32* sin_ = sdA + re; u32* sout = sdB + re;
  bool ldsm = false;
  int nt = 0;
  for (int round = 0; n > 0 && round < 4000; ++round) {
    u64 etag = (u64)(4095 - round) << 52;
    if (!ldsm) {
      // global Phase A: claim minima, ballot-compact (+ LDS shadow)
      for (int i = tid; i - lane < n; i += 1024) {
        bool inb = i < n;
        u32 sd = 0; u64 k = 0;
        if (inb) { sd = sin_[i]; k = kin[i]; }
        int s = sd >> 16, d = sd & 0xffff;
        bool alive = inb && !(dead_s[s] | dead_s[d]);
        if (alive) {
          u64 val = etag | k;
          if (val < bcur[s]) atomicMin(&bcur[s], val);
          if (d != s && val < bcur[d]) atomicMin(&bcur[d], val);
        }
        u64 m = __ballot(alive);
        if (m) {
          int lead = __ffsll((long long)m) - 1;
          int bse = 0;
          if (lane == lead) bse = atomicAdd(&lcnt, __popcll(m));
          bse = __shfl(bse, lead, 64);
          if (alive) {
            int j = bse + __popcll(m & ((1ull << lane) - 1ull));
            kout[j] = k;
            sout[j] = sd;
            if (j < TAILCAP) { tkey[j] = k; tsd[j] = sd; }
          }
        }
      }
      __syncthreads();
      int n2 = lcnt;
      if (n2 == 0) break;
      if (n2 <= TAILCAP) { ldsm = true; nt = n2; }
      // Phase B: locally-dominant edges match
      for (int i = tid; i < n2; i += 1024) {
        u32 sd; u64 k;
        if (ldsm) { sd = tsd[i]; k = tkey[i]; }
        else { sd = sout[i]; k = kout[i]; }
        int s = sd >> 16, d = sd & 0xffff;
        u64 val = etag | k;
        if (bcur[s] == val && (d == s || bcur[d] == val)) {
          matched[(u32)(k & 0xFFFFF)] = 1;
          dead_s[s] = 1;
          dead_s[d] = 1;
        }
      }
      if (tid == 0) lcnt = 0;
      __syncthreads();
      u64* tk = kin; kin = kout; kout = tk;
      u32* ts = sin_; sin_ = sout; sout = ts;
      n = n2;
    } else {
      // LDS Phase A over fixed nt entries; count alive
      int myal = 0;
      for (int i = tid; i < nt; i += 1024) {
        u32 sd = tsd[i];
        int s = sd >> 16, d = sd & 0xffff;
        if (dead_s[s] | dead_s[d]) continue;
        u64 val = etag | tkey[i];
        if (val < bcur[s]) atomicMin(&bcur[s], val);
        if (d != s && val < bcur[d]) atomicMin(&bcur[d], val);
        ++myal;
      }
      if (myal) atomicAdd(&lcnt, myal);
      __syncthreads();
      if (lcnt == 0) break;
      // LDS Phase B
      for (int i = tid; i < nt; i += 1024) {
        u32 sd = tsd[i];
        u64 k = tkey[i];
        int s = sd >> 16, d = sd & 0xffff;
        u64 val = etag | k;
        if (bcur[s] == val && (d == s || bcur[d] == val)) {
          matched[(u32)(k & 0xFFFFF)] = 1;
          dead_s[s] = 1;
          dead_s[d] = 1;
        }
      }
      if (tid == 0) lcnt = 0;
      __syncthreads();
    }
  }
  __syncthreads();
  for (int i = tid; i < per; i += 1024) dead[base + i] = dead_s[i];
}

// R7 two-phase cluster build (512 blocks); also zeroes cnt.
__global__ void k_build2(const u8* __restrict__ matched, const int* __restrict__ src,
                         const int* __restrict__ dst, const int* __restrict__ batch,
                         const int* __restrict__ dead, int* __restrict__ cluster,
                         int* __restrict__ new_batch, int* __restrict__ srcE,
                         int* __restrict__ nclus, float* __restrict__ gccnt,
                         int* __restrict__ cnt, int e, int n, int nc) {
  __shared__ int c_cnt, c_off, basep;
  __shared__ int sc[8];
  if (threadIdx.x == 0) { c_cnt = 0; c_off = 0; basep = 0; }
  if (threadIdx.x < 8) sc[threadIdx.x] = 0;
  __syncthreads();
  int nbk = gridDim.x;
  for (int i = blockIdx.x * blockDim.x + threadIdx.x; i < nc; i += nbk * blockDim.x) cnt[i] = 0;
  int ec = (e + nbk - 1) / nbk, es = blockIdx.x * ec, ee = es + ec; if (ee > e) ee = e;
  int nk = (n + nbk - 1) / nbk, ns = blockIdx.x * nk, ne = ns + nk; if (ne > n) ne = n;
  int my = 0;
  for (int i = es + threadIdx.x; i < ee; i += blockDim.x) if (matched[i]) ++my;
  for (int i = ns + threadIdx.x; i < ne; i += blockDim.x) if (!dead[i]) ++my;
  if (my) atomicAdd(&c_cnt, my);
  __syncthreads();
  if (threadIdx.x == 0 && c_cnt) basep = atomicAdd(nclus, c_cnt);
  __syncthreads();
  int bse = basep;
  for (int i = es + threadIdx.x; i < ee; i += blockDim.x) {
    if (!matched[i]) continue;
    int c = bse + atomicAdd(&c_off, 1);
    int s = src[i], d = dst[i];
    cluster[s] = c;
    cluster[d] = c;
    srcE[c] = i;
    int g = batch[s];
    new_batch[c] = g;
    if ((unsigned)g < 8u) atomicAdd(&sc[g], 1);
  }
  for (int i = ns + threadIdx.x; i < ne; i += blockDim.x) {
    if (dead[i]) continue;
    int c = bse + atomicAdd(&c_off, 1);
    cluster[i] = c;
    srcE[c] = ~i;  // singleton: encoded node
    int g = batch[i];
    new_batch[c] = g;
    if ((unsigned)g < 8u) atomicAdd(&sc[g], 1);
  }
  __syncthreads();
  if (threadIdx.x < 8 && sc[threadIdx.x] > 0)
    atomicAdd(&gccnt[threadIdx.x], (float)sc[threadIdx.x]);
}

#define HBITS 21
#define HMASK ((1u << HBITS) - 1u)

// cluster-driven new_x (wave per cluster) + hash-table init prologue.
__global__ void k_newx(const int* __restrict__ srcE, const int* __restrict__ src,
                       const int* __restrict__ dst, const float* __restrict__ score,
                       const int* __restrict__ nclusP, const float* __restrict__ h2,
                       float* __restrict__ new_x, u64* __restrict__ table, int n) {
  int idx = blockIdx.x * blockDim.x + threadIdx.x;
  if (idx < (1 << HBITS)) table[idx] = ~0ull;
  int c = idx >> 6;
  int lane = idx & 63;
  if (c >= n || c >= *nclusP) return;
  int v = srcE[c];
  float val;
  if (v >= 0) {
    int s = src[v], d = dst[v];
    val = h2[(size_t)s * 64 + lane];
    if (d != s) val += h2[(size_t)d * 64 + lane];
    val *= score[v];
  } else {
    val = h2[(size_t)(~v) * 64 + lane];
  }
  new_x[(size_t)c * 64 + lane] = val;
}

// coalesce(cluster[edge_index]): hash-dedup; dups -> sentinel n; counts kept.
__global__ void k_dedup(const int* __restrict__ src, const int* __restrict__ dst,
                        const int* __restrict__ cluster, u64* __restrict__ table,
                        int* __restrict__ ns, int* __restrict__ nd,
                        int* __restrict__ cnt, int e, int n) {
  int i = blockIdx.x * blockDim.x + threadIdx.x;
  if (i >= e) return;
  int cs_ = cluster[src[i]], cd_ = cluster[dst[i]];
  u64 kk = (u64)cs_ * (u64)(n + 1) + (u64)cd_;
  u32 pos = (u32)((kk * 0x9E3779B97F4A7C15ull) >> 43) & HMASK;
  while (true) {
    u64 old = atomicCAS(&table[pos], ~0ull, kk);
    if (old == ~0ull) {
      ns[i] = cs_; nd[i] = cd_;
      atomicAdd(&cnt[cd_], 1);
      return;
    }
    if (old == kk) { ns[i] = n; nd[i] = n; return; }
    pos = (pos + 1) & HMASK;
  }
}

// JK cat (partial-buffer reduce) + lin1 + relu + lin2 + log_softmax.
__global__ void k_head(const float* __restrict__ xs_part /*[4][64][512]*/,
                       const float* __restrict__ gn_part /*[64][8]*/,
                       const float* __restrict__ gccnt,
                       const float* __restrict__ l1w, const float* __restrict__ l1b,
                       const float* __restrict__ l2w, const float* __restrict__ l2b,
                       const int* __restrict__ gP, float* __restrict__ out, int C) {
  __shared__ float z[8][256];
  __shared__ float z1[8][64];
  __shared__ float z2[8][16];
  __shared__ float gnc[8];
  int G = *gP;
  int tid = threadIdx.x;
  if (tid < 8) {
    float s = 0.f;
    for (int b = 0; b < 64; ++b) s += gn_part[b * 8 + tid];
    gnc[tid] = s;
  }
  __syncthreads();
  int p = tid >> 6, f = tid & 63;
  for (int g = 0; g < G; ++g) {
    const float* xp = xs_part + (size_t)p * 64 * 512;
    float s = 0.f;
    for (int b = 0; b < 64; ++b) s += xp[b * 512 + g * 64 + f];
    float c = (p < 2) ? gnc[g] : gccnt[g];
    if (c < 1.f) c = 1.f;
    z[g][tid] = s / c;
  }
  __syncthreads();
  for (int idx = tid; idx < G * 64; idx += blockDim.x) {
    int g = idx >> 6, o = idx & 63;
    float a = l1b[o];
    for (int k = 0; k < 256; ++k) a = fmaf(z[g][k], l1w[o * 256 + k], a);
    z1[g][o] = a > 0.f ? a : 0.f;
  }
  __syncthreads();
  for (int idx = tid; idx < G * C; idx += blockDim.x) {
    int g = idx / C, c = idx % C;
    float a = l2b[c];
    for (int k = 0; k < 64; ++k) a = fmaf(z1[g][k], l2w[c * 64 + k], a);
    z2[g][c] = a;
  }
  __syncthreads();
  if (tid < G) {
    float m = z2[tid][0];
    for (int c = 1; c < C; ++c) m = fmaxf(m, z2[tid][c]);
    float s = 0.f;
    for (int c = 0; c < C; ++c) s += expf(z2[tid][c] - m);
    float lse = m + logf(s);
    for (int c = 0; c < C; ++c) out[tid * C + c] = z2[tid][c] - lse;
  }
}

extern "C" void kernel_launch(void* const* d_in, const int* in_sizes, int n_in,
                              void* d_out, int out_size, void* d_ws, size_t ws_size,
                              hipStream_t stream) {
  const float* x       = (const float*)d_in[0];
  const int*   ei      = (const int*)d_in[1];
  const int*   batch   = (const int*)d_in[2];
  const float* w_rel1  = (const float*)d_in[3];
  const float* b_rel1  = (const float*)d_in[4];
  const float* w_root1 = (const float*)d_in[5];
  const float* w_rel2  = (const float*)d_in[6];
  const float* b_rel2  = (const float*)d_in[7];
  const float* w_root2 = (const float*)d_in[8];
  const float* w_rel3  = (const float*)d_in[9];
  const float* b_rel3  = (const float*)d_in[10];
  const float* w_root3 = (const float*)d_in[11];
  const float* w_rel4  = (const float*)d_in[12];
  const float* b_rel4  = (const float*)d_in[13];
  const float* w_root4 = (const float*)d_in[14];
  const float* pool_w  = (const float*)d_in[15];
  const float* pool_b  = (const float*)d_in[16];
  const float* lin1_w  = (const float*)d_in[17];
  const float* lin1_b  = (const float*)d_in[18];
  const float* lin2_w  = (const float*)d_in[19];
  const float* lin2_b  = (const float*)d_in[20];
  const int*   gP      = (const int*)d_in[21];
  float* out = (float*)d_out;

  const int N = in_sizes[2];
  const int E = in_sizes[1] / 2;
  const int C = in_sizes[20];
  const int* src = ei;
  const int* dst = ei + E;

  // ---- workspace layout ----
  char* w = (char*)d_ws;
  auto alloc = [&](size_t bytes) -> char* {
    char* p = w;
    w += (bytes + 255) & ~(size_t)255;
    return p;
  };
  float* r      = (float*)alloc((size_t)N * 64 * 4);
  float* agg    = (float*)alloc((size_t)(N + 1) * 64 * 4);  // u / match lists / hash
  float* hA     = (float*)alloc((size_t)N * 64 * 4);        // h1 -> new_x -> h4
  float* hB     = (float*)alloc((size_t)N * 64 * 4);        // h2 -> h3
  float* score  = (float*)alloc((size_t)E * 4);
  int*   colbuf = (int*)alloc((size_t)E * 8);               // col + eid
  int*   listA  = (int*)alloc((size_t)E * 4);               // aN -> ns
  int*   listB  = (int*)alloc((size_t)E * 4);               // bN -> nd
  int*   rowptr = (int*)alloc((size_t)(N + 2) * 4);
  int*   pos    = (int*)alloc((size_t)(N + 2) * 4);         // also srcE
  char* zstart = w;                                         // zeroed block
  int*   cnt       = (int*)alloc((size_t)(N + 2) * 4);
  int*   bsum      = (int*)alloc(1024);
  int*   dead      = (int*)alloc((size_t)N * 4);
  u8*    matched   = (u8*)alloc((size_t)E);
  int*   cluster   = (int*)alloc((size_t)N * 4);
  int*   new_batch = (int*)alloc((size_t)N * 4);
  float* xs_part   = (float*)alloc((size_t)4 * 64 * 512 * 4);  // per-stage partials
  float* gn_part   = (float*)alloc((size_t)64 * 8 * 4);
  float* small     = (float*)alloc(16384);
  size_t zbytes = (size_t)(w - zstart);
  if ((size_t)(w - (char*)d_ws) > ws_size) return;  // fail loudly

  int*   col = colbuf;         // CSR src per slot
  int*   eid = colbuf + E;     // CSR original-edge id per slot
  float* aN  = (float*)listA;  // alias: dots dead before ns/nd used
  float* bN  = (float*)listB;
  float* uB  = agg;            // u for all convs (agg phase-disjoint)
  u64*   keyA = (u64*)agg;     // match lists (after conv2 gfin2, before build)
  u64*   keyB = keyA + E;
  u32*   sdA  = (u32*)(keyB + E);
  u32*   sdB  = sdA + E;
  u64*   table = (u64*)agg;    // hash (after match, before conv3)
  int*   srcE = pos;           // alias: pos re-filled later by 2nd scan_out

  float* gccnt  = small;                 // [8]
  int*   nclusP = (int*)(small + 16);

  const int TB = 256;
  const int gN = (N + TB - 1) / TB;
  const int gE = (E + TB - 1) / TB;
  const int gE1k = (E + 1023) >> 10;
  const int gNw = (int)(((size_t)N * 64 + TB - 1) / TB);  // wave per node
  const int swz = (gNw % 8 == 0) ? 1 : 0;
  const int nc = N + 2;
  const int nb = (nc + 1023) / 1024;

  hipMemsetAsync(zstart, 0, zbytes, stream);

  // ---- CSR for original edges ----
  k_count<<<gE1k, TB, 0, stream>>>(dst, cnt, E);
  k_scan_sums<<<nb, TB, 0, stream>>>(cnt, bsum, nc);
  k_scan_tops<<<1, 128, 0, stream>>>(bsum, nb);
  k_scan_out<<<nb, TB, 0, stream>>>(cnt, bsum, rowptr, pos, nc);
  k_fill<<<gE, TB, 0, stream>>>(src, dst, pos, col, eid, E, N);

  // ---- conv1 (F=128 -> 64) ----
  k_transform2<128><<<gN, TB, 0, stream>>>(x, w_rel1, w_root1, b_rel1, nullptr, r, uB, N);
  k_gfin2<<<gNw, TB, 0, stream>>>(r, uB, rowptr, col, batch, gP, nullptr, hA,
                                  nullptr, nullptr, nullptr, xs_part + 0 * 32768, gn_part, N, swz);

  // ---- conv2 (64 -> 64, + score dots) ----
  k_transform2<64><<<gN, TB, 0, stream>>>(hA, w_rel2, w_root2, b_rel2, nullptr, r, uB, N);
  k_gfin2<<<gNw, TB, 0, stream>>>(r, uB, rowptr, col, batch, gP, nullptr, hB,
                                  pool_w, aN, bN, xs_part + 1 * 32768, nullptr, N, swz);

  // ---- scoring in CSR order (per-graph contiguous) ----
  k_score_csr<<<gN, TB, 0, stream>>>(aN, bN, pool_b, rowptr, col, eid, gP,
                                     score, keyA, sdA, N);

  // ---- greedy matching (per-graph workgroup, LDS state + LDS tail) ----
  k_match_wg<<<8, 1024, 0, stream>>>(rowptr, gP, keyA, keyB, sdA, sdB, dead, matched, N);

  // ---- clusters (two-phase), new_x (+hash init), dedup + pooled CSR ----
  k_build2<<<512, TB, 0, stream>>>(matched, src, dst, batch, dead, cluster, new_batch,
                                   srcE, nclusP, gccnt, cnt, E, N, nc);
  k_newx<<<gNw, TB, 0, stream>>>(srcE, src, dst, score, nclusP, hB, hA, table, N);
  k_dedup<<<gE, TB, 0, stream>>>(src, dst, cluster, table, listA, listB, cnt, E, N);
  k_scan_sums<<<nb, TB, 0, stream>>>(cnt, bsum, nc);
  k_scan_tops<<<1, 128, 0, stream>>>(bsum, nb);
  k_scan_out<<<nb, TB, 0, stream>>>(cnt, bsum, rowptr, pos, nc);
  k_fill<<<gE, TB, 0, stream>>>(listA, listB, pos, col, nullptr, E, N);

  // ---- conv3 (64 -> 64, pooled) ----
  k_transform2<64><<<gN, TB, 0, stream>>>(hA, w_rel3, w_root3, b_rel3, nclusP, r, uB, N);
  k_gfin2<<<gNw, TB, 0, stream>>>(r, uB, rowptr, col, new_batch, gP, nclusP, hB,
                                  nullptr, nullptr, nullptr, xs_part + 2 * 32768, nullptr, N, 0);

  // ---- conv4 (64 -> 64, pooled) ----
  k_transform2<64><<<gN, TB, 0, stream>>>(hB, w_rel4, w_root4, b_rel4, nclusP, r, uB, N);
  k_gfin2<<<gNw, TB, 0, stream>>>(r, uB, rowptr, col, new_batch, gP, nclusP, hA,
                                  nullptr, nullptr, nullptr, xs_part + 3 * 32768, nullptr, N, 0);

  // ---- head ----
  k_head<<<1, TB, 0, stream>>>(xs_part, gn_part, gccnt, lin1_w, lin1_b, lin2_w, lin2_b, gP, out, C);
}

// Round 10
// 1562.839 us; speedup vs baseline: 1.2646x; 1.0555x over previous
//
#include <hip/hip_runtime.h>
#include <stdint.h>

typedef unsigned long long u64;
typedef unsigned int u32;
typedef unsigned char u8;

// ---------------------------------------------------------------------------
// EdgePool GNN pipeline.  N=100000, E=800000, F=128, H=64, G=8, C=10. f32.
// R1 two-stage gmp · R2 dst-CSR gather · R4 match state in LDS · R5 XCD
// swizzle + epoch bcur + no-max softmax · R7 wave-per-node gfin2 + partial
// gmp flush + two-phase build · R8 CSR-ordered scoring.
// R9: matching round 0 moved grid-wide (256 CUs, was 8): score_csr also
//     atomicMins round-0 keys into global bcur0; k_match0 applies the
//     round-0 test; k_list0 builds the compacted alive list (~40% of E).
//     k_match_wg keeps compacted global rounds (R5 structure) and switches
//     to a single-wave LDS tail at alive<=2048 (no __syncthreads; LDS
//     ordering via __threadfence_block; in-register chunk compaction).
//     R8's fixed-nt 1024-thread tail (regressed 278->315us) removed.
// ---------------------------------------------------------------------------

// r = x@w_rel^T, u = x@w_root^T + bias  (both weights staged in LDS)
template <int K>
__global__ void k_transform2(const float* __restrict__ x, const float* __restrict__ wrel,
                             const float* __restrict__ wroot, const float* __restrict__ bias,
                             const int* __restrict__ nvP, float* __restrict__ r,
                             float* __restrict__ u, int n) {
  __shared__ float ws[64 * K];
  __shared__ float ws2[64 * K];
  for (int i = threadIdx.x; i < 64 * K; i += blockDim.x) { ws[i] = wrel[i]; ws2[i] = wroot[i]; }
  __syncthreads();
  int node = blockIdx.x * blockDim.x + threadIdx.x;
  if (node >= n) return;
  if (nvP && node >= *nvP) return;
  const float* xr = x + (size_t)node * K;
  float acc[64], acc2[64];
#pragma unroll
  for (int o = 0; o < 64; ++o) { acc[o] = 0.f; acc2[o] = bias[o]; }
  for (int k = 0; k < K; k += 4) {
    float4 xv = *reinterpret_cast<const float4*>(xr + k);
#pragma unroll
    for (int o = 0; o < 64; ++o) {
      float4 wv = *reinterpret_cast<const float4*>(&ws[o * K + k]);
      acc[o] = fmaf(xv.x, wv.x, acc[o]);
      acc[o] = fmaf(xv.y, wv.y, acc[o]);
      acc[o] = fmaf(xv.z, wv.z, acc[o]);
      acc[o] = fmaf(xv.w, wv.w, acc[o]);
      float4 w2 = *reinterpret_cast<const float4*>(&ws2[o * K + k]);
      acc2[o] = fmaf(xv.x, w2.x, acc2[o]);
      acc2[o] = fmaf(xv.y, w2.y, acc2[o]);
      acc2[o] = fmaf(xv.z, w2.z, acc2[o]);
      acc2[o] = fmaf(xv.w, w2.w, acc2[o]);
    }
  }
  float4* rr = reinterpret_cast<float4*>(r + (size_t)node * 64);
  float4* ur = reinterpret_cast<float4*>(u + (size_t)node * 64);
#pragma unroll
  for (int o = 0; o < 16; ++o) {
    rr[o] = make_float4(acc[4 * o], acc[4 * o + 1], acc[4 * o + 2], acc[4 * o + 3]);
    ur[o] = make_float4(acc2[4 * o], acc2[4 * o + 1], acc2[4 * o + 2], acc2[4 * o + 3]);
  }
}

// dst-degree count; 1024-edge chunks
__global__ void k_count(const int* __restrict__ dst, int* __restrict__ cnt, int e) {
  int base = blockIdx.x << 10;
#pragma unroll
  for (int k = 0; k < 4; ++k) {
    int i = base + k * 256 + threadIdx.x;
    if (i < e) atomicAdd(&cnt[dst[i]], 1);
  }
}

// ---- scan over nc ints ----
__global__ void k_scan_sums(const int* __restrict__ in, int* __restrict__ bsum, int n) {
  __shared__ int sd[256];
  int base = blockIdx.x << 10;
  int s = 0;
  for (int j = threadIdx.x; j < 1024; j += 256) {
    int id = base + j;
    s += (id < n) ? in[id] : 0;
  }
  sd[threadIdx.x] = s;
  __syncthreads();
  for (int w = 128; w > 0; w >>= 1) {
    if (threadIdx.x < w) sd[threadIdx.x] += sd[threadIdx.x + w];
    __syncthreads();
  }
  if (threadIdx.x == 0) bsum[blockIdx.x] = sd[0];
}
__global__ void k_scan_tops(int* __restrict__ bsum, int nb) {
  __shared__ int sd[128];
  int tid = threadIdx.x;
  int v = (tid < nb) ? bsum[tid] : 0;
  sd[tid] = v;
  __syncthreads();
  for (int off = 1; off < 128; off <<= 1) {
    int add = (tid >= off) ? sd[tid - off] : 0;
    __syncthreads();
    sd[tid] += add;
    __syncthreads();
  }
  if (tid < nb) bsum[tid] = sd[tid] - v;  // exclusive
}
__global__ void k_scan_out(const int* __restrict__ in, const int* __restrict__ bsum,
                           int* __restrict__ rowptr, int* __restrict__ pos, int n) {
  __shared__ int sd[256];
  int base = blockIdx.x << 10;
  int i0 = base + threadIdx.x * 4;
  int v0 = 0, v1 = 0, v2 = 0, v3 = 0;
  if (i0 < n) v0 = in[i0];
  if (i0 + 1 < n) v1 = in[i0 + 1];
  if (i0 + 2 < n) v2 = in[i0 + 2];
  if (i0 + 3 < n) v3 = in[i0 + 3];
  sd[threadIdx.x] = v0 + v1 + v2 + v3;
  __syncthreads();
  for (int off = 1; off < 256; off <<= 1) {
    int add = (threadIdx.x >= off) ? sd[threadIdx.x - off] : 0;
    __syncthreads();
    sd[threadIdx.x] += add;
    __syncthreads();
  }
  int excl = bsum[blockIdx.x] + (threadIdx.x ? sd[threadIdx.x - 1] : 0);
  if (i0 < n) { rowptr[i0] = excl; pos[i0] = excl; }
  excl += v0;
  if (i0 + 1 < n) { rowptr[i0 + 1] = excl; pos[i0 + 1] = excl; }
  excl += v1;
  if (i0 + 2 < n) { rowptr[i0 + 2] = excl; pos[i0 + 2] = excl; }
  excl += v2;
  if (i0 + 3 < n) { rowptr[i0 + 3] = excl; pos[i0 + 3] = excl; }
}

// CSR fill: col = src, eid = original edge index
__global__ void k_fill(const int* __restrict__ src, const int* __restrict__ dst,
                       int* __restrict__ pos, int* __restrict__ col,
                       int* __restrict__ eid, int e, int n) {
  int i = blockIdx.x * blockDim.x + threadIdx.x;
  if (i >= e) return;
  int d = dst[i];
  if (d >= n) return;  // sentinel (pooled duplicates)
  int j = atomicAdd(&pos[d], 1);
  col[j] = src[i];
  if (eid) eid[j] = i;
}

// R7 fused conv tail: wave-per-node gather + mean + relu + h-write (+dots),
// gmp accumulated in LDS, flushed to 64 partial buffers (presence-masked).
__global__ void k_gfin2(const float* __restrict__ r, const float* __restrict__ u,
                        const int* __restrict__ rowptr, const int* __restrict__ col,
                        const int* __restrict__ batch, const int* __restrict__ gP,
                        const int* __restrict__ nvP, float* __restrict__ h,
                        const float* __restrict__ pw, float* __restrict__ aN,
                        float* __restrict__ bN, float* __restrict__ xs_part /*[64][512]*/,
                        float* __restrict__ gn_part /*[64][8] or null*/, int n, int swz) {
  __shared__ float sacc[512];
  __shared__ float scnt8[8];
  __shared__ float pws[128];
  __shared__ int pres;
  int G = *gP;
  int nv = nvP ? *nvP : n;
  if (nv > n) nv = n;
  for (int i = threadIdx.x; i < 512; i += 256) sacc[i] = 0.f;
  if (threadIdx.x < 8) scnt8[threadIdx.x] = 0.f;
  if (threadIdx.x == 0) pres = 0;
  if (pw && threadIdx.x < 128) pws[threadIdx.x] = pw[threadIdx.x];
  __syncthreads();
  int b = blockIdx.x;
  if (swz) { int chunk = gridDim.x >> 3; b = (b & 7) * chunk + (b >> 3); }
  int lane = threadIdx.x & 63, w = threadIdx.x >> 6;
  int node = b * 4 + w;
  if (node < nv) {
    int bg = rowptr[node], e2 = rowptr[node + 1];
    float s = 0.f;
    for (int j = bg; j < e2; ++j) s += r[(size_t)col[j] * 64 + lane];
    int deg = e2 - bg;
    float inv = deg > 0 ? 1.f / (float)deg : 0.f;
    float v = fmaf(s, inv, u[(size_t)node * 64 + lane]);
    v = v > 0.f ? v : 0.f;
    h[(size_t)node * 64 + lane] = v;
    if (pw) {
      float d1 = v * pws[lane];
      float d2 = v * pws[64 + lane];
#pragma unroll
      for (int off = 32; off > 0; off >>= 1) {
        d1 += __shfl_down(d1, off, 64);
        d2 += __shfl_down(d2, off, 64);
      }
      if (lane == 0) { aN[node] = d1; bN[node] = d2; }
    }
    int g = batch[node];
    if ((unsigned)g < 8u && g < G) {
      atomicAdd(&sacc[g * 64 + lane], v);
      if (lane == 0) {
        atomicOr(&pres, 1 << g);
        if (gn_part) atomicAdd(&scnt8[g], 1.f);
      }
    }
  }
  __syncthreads();
  int pm = pres;
  if (!pm) return;
  int buf = blockIdx.x & 63;
  float* xp = xs_part + buf * 512;
  for (int i = threadIdx.x; i < 512; i += 256) {
    if ((pm >> (i >> 6)) & 1) {
      float s2 = sacc[i];
      if (s2 != 0.f) atomicAdd(&xp[i], s2);
    }
  }
  if (gn_part && threadIdx.x < 8) {
    float c = scnt8[threadIdx.x];
    if (c != 0.f) atomicAdd(&gn_part[buf * 8 + threadIdx.x], c);
  }
}

// R8/R9: CSR-ordered scoring + round-0 priority claim into global bcur0.
// Thread per dst node: softmax over in-edges; key/sd into CSR slots;
// per-edge s-side atomicMin + one row-min d-side atomicMin.
__global__ void k_score_csr(const float* __restrict__ aN, const float* __restrict__ bN,
                            const float* __restrict__ pbp, const int* __restrict__ rowptr,
                            const int* __restrict__ col, const int* __restrict__ eid,
                            const int* __restrict__ gP, float* __restrict__ score,
                            u64* __restrict__ keyA, u32* __restrict__ sdA,
                            u64* __restrict__ bcur0, int N) {
  int d = blockIdx.x * blockDim.x + threadIdx.x;
  if (d >= N) return;
  int b = rowptr[d], e2 = rowptr[d + 1];
  if (b == e2) return;
  float bd = bN[d] + pbp[0];
  float den = 0.f;
  for (int j = b; j < e2; ++j) den += expf(aN[col[j]] + bd);
  int per = N / *gP;
  int g = d / per;
  int base = g * per;
  u32 dl = (u32)(d - base);
  u64 rmin = ~0ull;
  for (int j = b; j < e2; ++j) {
    int s = col[j];
    int ei = eid[j];
    float sc = expf(aN[s] + bd) / den + 0.5f;
    score[ei] = sc;
    u64 k = ((u64)(u32)(~__float_as_uint(sc)) << 20) | (u32)ei;
    keyA[j] = k;
    sdA[j] = ((u32)(s - base) << 16) | dl;
    atomicMin(&bcur0[s], k);
    if (k < rmin) rmin = k;
  }
  atomicMin(&bcur0[d], rmin);
}

// R9: grid-wide round-0 match test (bcur0 read-only -> deterministic).
__global__ void k_match0(const int* __restrict__ rowptr, const int* __restrict__ gP,
                         const u64* __restrict__ keyA, const u32* __restrict__ sdA,
                         const u64* __restrict__ bcur0, u8* __restrict__ matched,
                         int* __restrict__ dead, int N) {
  int d = blockIdx.x * blockDim.x + threadIdx.x;
  if (d >= N) return;
  int b = rowptr[d], e2 = rowptr[d + 1];
  if (b == e2) return;
  int per = N / *gP;
  int base = (d / per) * per;
  u64 kd = bcur0[d];
  for (int j = b; j < e2; ++j) {
    u64 k = keyA[j];
    int gs = base + (int)(sdA[j] >> 16);
    if (bcur0[gs] == k && (gs == d || kd == k)) {
      matched[(u32)(k & 0xFFFFF)] = 1;
      dead[gs] = 1;
      dead[d] = 1;
    }
  }
}

// R9: grid-wide alive-list build (dead stable/read-only here).
__global__ void k_list0(const int* __restrict__ rowptr, const int* __restrict__ gP,
                        const u64* __restrict__ keyA, const u32* __restrict__ sdA,
                        const int* __restrict__ dead, u64* __restrict__ keyB,
                        u32* __restrict__ sdB, int* __restrict__ gposM, int N) {
  __shared__ int scnt[8], sbase[8];
  if (threadIdx.x < 8) scnt[threadIdx.x] = 0;
  __syncthreads();
  int d = blockIdx.x * blockDim.x + threadIdx.x;
  int g = -1, b = 0, e2 = 0, base = 0, myn = 0, rank = 0;
  if (d < N && !dead[d]) {
    b = rowptr[d]; e2 = rowptr[d + 1];
    if (b < e2) {
      int per = N / *gP;
      g = d / per; base = g * per;
      for (int j = b; j < e2; ++j)
        if (!dead[base + (int)(sdA[j] >> 16)]) ++myn;
      if (myn) rank = atomicAdd(&scnt[g], myn);
    }
  }
  __syncthreads();
  if (threadIdx.x < 8 && scnt[threadIdx.x])
    sbase[threadIdx.x] = atomicAdd(&gposM[threadIdx.x], scnt[threadIdx.x]);
  __syncthreads();
  if (g < 0 || !myn) return;
  int off = rowptr[base] + sbase[g] + rank;
  for (int j = b; j < e2; ++j) {
    if (!dead[base + (int)(sdA[j] >> 16)]) {
      keyB[off] = keyA[j];
      sdB[off] = sdA[j];
      ++off;
    }
  }
}

// Per-graph exact greedy matching from round 1. Compacted global rounds
// (R5 structure) + single-wave LDS tail at alive<=WAVECAP (no barriers;
// __threadfence_block orders LDS between phases; in-register compaction).
#define PERMAX 12544
#define WAVECAP 2048
__global__ __launch_bounds__(1024) void k_match_wg(
    const int* __restrict__ rowptr, const int* __restrict__ gP,
    const int* __restrict__ gposM,
    u64* __restrict__ keyB, u64* __restrict__ keyA,
    u32* __restrict__ sdB, u32* __restrict__ sdA,
    int* __restrict__ dead, u8* __restrict__ matched, int N) {
  __shared__ u64 bcur[PERMAX];
  __shared__ u8 dead_s[PERMAX];
  __shared__ u64 tkey[WAVECAP];
  __shared__ u32 tsd[WAVECAP];
  __shared__ int lcnt;
  int G = *gP;
  int g = blockIdx.x;
  if (g >= G) return;
  int per = N / G;
  if (per > PERMAX) per = PERMAX;
  int base = g * per;
  int re = rowptr[base];
  int n = gposM[g];
  int tid = threadIdx.x, lane = tid & 63;
  for (int i = tid; i < per; i += 1024) {
    bcur[i] = ~0ull;
    dead_s[i] = dead[base + i] ? 1 : 0;
  }
  if (tid == 0) lcnt = 0;
  __syncthreads();
  u64* kin = keyB + re; u64* kout = keyA + re;
  u32* sin_ = sdB + re; u32* sout = sdA + re;
  for (int round = 1; n > 0 && round < 4000; ++round) {
    u64 etag = (u64)(4095 - round) << 52;
    // Phase A: claim minima, ballot-compact (+ shadow into LDS when small)
    for (int i = tid; i - lane < n; i += 1024) {
      bool inb = i < n;
      u32 sd = 0; u64 k = 0;
      if (inb) { sd = sin_[i]; k = kin[i]; }
      int s = sd >> 16, d = sd & 0xffff;
      bool alive = inb && !(dead_s[s] | dead_s[d]);
      if (alive) {
        u64 val = etag | k;
        if (val < bcur[s]) atomicMin(&bcur[s], val);
        if (d != s && val < bcur[d]) atomicMin(&bcur[d], val);
      }
      u64 m = __ballot(alive);
      if (m) {
        int lead = __ffsll((long long)m) - 1;
        int bse = 0;
        if (lane == lead) bse = atomicAdd(&lcnt, __popcll(m));
        bse = __shfl(bse, lead, 64);
        if (alive) {
          int j = bse + __popcll(m & ((1ull << lane) - 1ull));
          kout[j] = k;
          sout[j] = sd;
          if (j < WAVECAP) { tkey[j] = k; tsd[j] = sd; }
        }
      }
    }
    __syncthreads();
    int n2 = lcnt;
    if (n2 == 0) break;
    bool totail = (n2 <= WAVECAP);
    // Phase B: locally-dominant edges match
    for (int i = tid; i < n2; i += 1024) {
      u32 sd; u64 k;
      if (totail) { sd = tsd[i]; k = tkey[i]; }
      else { sd = sout[i]; k = kout[i]; }
      int s = sd >> 16, d = sd & 0xffff;
      u64 val = etag | k;
      if (bcur[s] == val && (d == s || bcur[d] == val)) {
        matched[(u32)(k & 0xFFFFF)] = 1;
        dead_s[s] = 1;
        dead_s[d] = 1;
      }
    }
    if (tid == 0) lcnt = 0;
    __syncthreads();
    if (totail) {
      if (tid < 64) {
        // single-wave tail: rounds at LDS latency, no block barriers
        int nt = n2;
        int rr = round + 1;
        while (nt > 0 && rr < 4000) {
          u64 et2 = (u64)(4095 - rr) << 52;
          // Phase A (wave)
          for (int i = lane; i < nt; i += 64) {
            u32 sd = tsd[i];
            int s = sd >> 16, d = sd & 0xffff;
            if (dead_s[s] | dead_s[d]) continue;
            u64 val = et2 | tkey[i];
            if (val < bcur[s]) atomicMin(&bcur[s], val);
            if (d != s && val < bcur[d]) atomicMin(&bcur[d], val);
          }
          __threadfence_block();
          // Phase B + in-register chunk compaction (write cursor <= read)
          int wc = 0;
          for (int i0 = 0; i0 < nt; i0 += 64) {
            int i = i0 + lane;
            u32 sd = 0; u64 k = 0;
            bool have = i < nt;
            if (have) { sd = tsd[i]; k = tkey[i]; }
            int s = sd >> 16, d = sd & 0xffff;
            bool alive = false;
            if (have && !(dead_s[s] | dead_s[d])) {
              u64 val = et2 | k;
              if (bcur[s] == val && (d == s || bcur[d] == val)) {
                matched[(u32)(k & 0xFFFFF)] = 1;
                dead_s[s] = 1;
                dead_s[d] = 1;
              } else {
                alive = true;
              }
            }
            u64 m = __ballot(alive);
            int idx = wc + __popcll(m & ((1ull << lane) - 1ull));
            if (alive) { tkey[idx] = k; tsd[idx] = sd; }
            wc += (int)__popcll(m);
          }
          nt = wc;
          ++rr;
          __threadfence_block();
        }
      }
      __syncthreads();
      break;
    }
    u64* tk = kin; kin = kout; kout = tk;
    u32* ts = sin_; sin_ = sout; sout = ts;
    n = n2;
  }
  __syncthreads();
  for (int i = tid; i < per; i += 1024) dead[base + i] = dead_s[i];
}

// R7 two-phase cluster build (512 blocks); also zeroes cnt.
__global__ void k_build2(const u8* __restrict__ matched, const int* __restrict__ src,
                         const int* __restrict__ dst, const int* __restrict__ batch,
                         const int* __restrict__ dead, int* __restrict__ cluster,
                         int* __restrict__ new_batch, int* __restrict__ srcE,
                         int* __restrict__ nclus, float* __restrict__ gccnt,
                         int* __restrict__ cnt, int e, int n, int nc) {
  __shared__ int c_cnt, c_off, basep;
  __shared__ int sc[8];
  if (threadIdx.x == 0) { c_cnt = 0; c_off = 0; basep = 0; }
  if (threadIdx.x < 8) sc[threadIdx.x] = 0;
  __syncthreads();
  int nbk = gridDim.x;
  for (int i = blockIdx.x * blockDim.x + threadIdx.x; i < nc; i += nbk * blockDim.x) cnt[i] = 0;
  int ec = (e + nbk - 1) / nbk, es = blockIdx.x * ec, ee = es + ec; if (ee > e) ee = e;
  int nk = (n + nbk - 1) / nbk, ns = blockIdx.x * nk, ne = ns + nk; if (ne > n) ne = n;
  int my = 0;
  for (int i = es + threadIdx.x; i < ee; i += blockDim.x) if (matched[i]) ++my;
  for (int i = ns + threadIdx.x; i < ne; i += blockDim.x) if (!dead[i]) ++my;
  if (my) atomicAdd(&c_cnt, my);
  __syncthreads();
  if (threadIdx.x == 0 && c_cnt) basep = atomicAdd(nclus, c_cnt);
  __syncthreads();
  int bse = basep;
  for (int i = es + threadIdx.x; i < ee; i += blockDim.x) {
    if (!matched[i]) continue;
    int c = bse + atomicAdd(&c_off, 1);
    int s = src[i], d = dst[i];
    cluster[s] = c;
    cluster[d] = c;
    srcE[c] = i;
    int g = batch[s];
    new_batch[c] = g;
    if ((unsigned)g < 8u) atomicAdd(&sc[g], 1);
  }
  for (int i = ns + threadIdx.x; i < ne; i += blockDim.x) {
    if (dead[i]) continue;
    int c = bse + atomicAdd(&c_off, 1);
    cluster[i] = c;
    srcE[c] = ~i;  // singleton: encoded node
    int g = batch[i];
    new_batch[c] = g;
    if ((unsigned)g < 8u) atomicAdd(&sc[g], 1);
  }
  __syncthreads();
  if (threadIdx.x < 8 && sc[threadIdx.x] > 0)
    atomicAdd(&gccnt[threadIdx.x], (float)sc[threadIdx.x]);
}

#define HBITS 21
#define HMASK ((1u << HBITS) - 1u)

// cluster-driven new_x (wave per cluster) + hash-table init prologue.
__global__ void k_newx(const int* __restrict__ srcE, const int* __restrict__ src,
                       const int* __restrict__ dst, const float* __restrict__ score,
                       const int* __restrict__ nclusP, const float* __restrict__ h2,
                       float* __restrict__ new_x, u64* __restrict__ table, int n) {
  int idx = blockIdx.x * blockDim.x + threadIdx.x;
  if (idx < (1 << HBITS)) table[idx] = ~0ull;
  int c = idx >> 6;
  int lane = idx & 63;
  if (c >= n || c >= *nclusP) return;
  int v = srcE[c];
  float val;
  if (v >= 0) {
    int s = src[v], d = dst[v];
    val = h2[(size_t)s * 64 + lane];
    if (d != s) val += h2[(size_t)d * 64 + lane];
    val *= score[v];
  } else {
    val = h2[(size_t)(~v) * 64 + lane];
  }
  new_x[(size_t)c * 64 + lane] = val;
}

// coalesce(cluster[edge_index]): hash-dedup; dups -> sentinel n; counts kept.
__global__ void k_dedup(const int* __restrict__ src, const int* __restrict__ dst,
                        const int* __restrict__ cluster, u64* __restrict__ table,
                        int* __restrict__ ns, int* __restrict__ nd,
                        int* __restrict__ cnt, int e, int n) {
  int i = blockIdx.x * blockDim.x + threadIdx.x;
  if (i >= e) return;
  int cs_ = cluster[src[i]], cd_ = cluster[dst[i]];
  u64 kk = (u64)cs_ * (u64)(n + 1) + (u64)cd_;
  u32 pos = (u32)((kk * 0x9E3779B97F4A7C15ull) >> 43) & HMASK;
  while (true) {
    u64 old = atomicCAS(&table[pos], ~0ull, kk);
    if (old == ~0ull) {
      ns[i] = cs_; nd[i] = cd_;
      atomicAdd(&cnt[cd_], 1);
      return;
    }
    if (old == kk) { ns[i] = n; nd[i] = n; return; }
    pos = (pos + 1) & HMASK;
  }
}

// JK cat (partial-buffer reduce) + lin1 + relu + lin2 + log_softmax.
__global__ void k_head(const float* __restrict__ xs_part /*[4][64][512]*/,
                       const float* __restrict__ gn_part /*[64][8]*/,
                       const float* __restrict__ gccnt,
                       const float* __restrict__ l1w, const float* __restrict__ l1b,
                       const float* __restrict__ l2w, const float* __restrict__ l2b,
                       const int* __restrict__ gP, float* __restrict__ out, int C) {
  __shared__ float z[8][256];
  __shared__ float z1[8][64];
  __shared__ float z2[8][16];
  __shared__ float gnc[8];
  int G = *gP;
  int tid = threadIdx.x;
  if (tid < 8) {
    float s = 0.f;
    for (int b = 0; b < 64; ++b) s += gn_part[b * 8 + tid];
    gnc[tid] = s;
  }
  __syncthreads();
  int p = tid >> 6, f = tid & 63;
  for (int g = 0; g < G; ++g) {
    const float* xp = xs_part + (size_t)p * 64 * 512;
    float s = 0.f;
    for (int b = 0; b < 64; ++b) s += xp[b * 512 + g * 64 + f];
    float c = (p < 2) ? gnc[g] : gccnt[g];
    if (c < 1.f) c = 1.f;
    z[g][tid] = s / c;
  }
  __syncthreads();
  for (int idx = tid; idx < G * 64; idx += blockDim.x) {
    int g = idx >> 6, o = idx & 63;
    float a = l1b[o];
    for (int k = 0; k < 256; ++k) a = fmaf(z[g][k], l1w[o * 256 + k], a);
    z1[g][o] = a > 0.f ? a : 0.f;
  }
  __syncthreads();
  for (int idx = tid; idx < G * C; idx += blockDim.x) {
    int g = idx / C, c = idx % C;
    float a = l2b[c];
    for (int k = 0; k < 64; ++k) a = fmaf(z1[g][k], l2w[c * 64 + k], a);
    z2[g][c] = a;
  }
  __syncthreads();
  if (tid < G) {
    float m = z2[tid][0];
    for (int c = 1; c < C; ++c) m = fmaxf(m, z2[tid][c]);
    float s = 0.f;
    for (int c = 0; c < C; ++c) s += expf(z2[tid][c] - m);
    float lse = m + logf(s);
    for (int c = 0; c < C; ++c) out[tid * C + c] = z2[tid][c] - lse;
  }
}

extern "C" void kernel_launch(void* const* d_in, const int* in_sizes, int n_in,
                              void* d_out, int out_size, void* d_ws, size_t ws_size,
                              hipStream_t stream) {
  const float* x       = (const float*)d_in[0];
  const int*   ei      = (const int*)d_in[1];
  const int*   batch   = (const int*)d_in[2];
  const float* w_rel1  = (const float*)d_in[3];
  const float* b_rel1  = (const float*)d_in[4];
  const float* w_root1 = (const float*)d_in[5];
  const float* w_rel2  = (const float*)d_in[6];
  const float* b_rel2  = (const float*)d_in[7];
  const float* w_root2 = (const float*)d_in[8];
  const float* w_rel3  = (const float*)d_in[9];
  const float* b_rel3  = (const float*)d_in[10];
  const float* w_root3 = (const float*)d_in[11];
  const float* w_rel4  = (const float*)d_in[12];
  const float* b_rel4  = (const float*)d_in[13];
  const float* w_root4 = (const float*)d_in[14];
  const float* pool_w  = (const float*)d_in[15];
  const float* pool_b  = (const float*)d_in[16];
  const float* lin1_w  = (const float*)d_in[17];
  const float* lin1_b  = (const float*)d_in[18];
  const float* lin2_w  = (const float*)d_in[19];
  const float* lin2_b  = (const float*)d_in[20];
  const int*   gP      = (const int*)d_in[21];
  float* out = (float*)d_out;

  const int N = in_sizes[2];
  const int E = in_sizes[1] / 2;
  const int C = in_sizes[20];
  const int* src = ei;
  const int* dst = ei + E;

  // ---- workspace layout ----
  char* w = (char*)d_ws;
  auto alloc = [&](size_t bytes) -> char* {
    char* p = w;
    w += (bytes + 255) & ~(size_t)255;
    return p;
  };
  float* r      = (float*)alloc((size_t)N * 64 * 4);
  float* agg    = (float*)alloc((size_t)(N + 1) * 64 * 4);  // u / match lists / hash
  float* hA     = (float*)alloc((size_t)N * 64 * 4);        // h1 -> new_x -> h4
  float* hB     = (float*)alloc((size_t)N * 64 * 4);        // h2 -> h3
  float* score  = (float*)alloc((size_t)E * 4);
  int*   colbuf = (int*)alloc((size_t)E * 8);               // col + eid
  int*   listA  = (int*)alloc((size_t)E * 4);               // aN -> ns
  int*   listB  = (int*)alloc((size_t)E * 4);               // bN -> nd
  int*   rowptr = (int*)alloc((size_t)(N + 2) * 4);
  int*   pos    = (int*)alloc((size_t)(N + 2) * 4);         // also srcE
  char* zstart = w;                                         // zeroed block
  int*   cnt       = (int*)alloc((size_t)(N + 2) * 4);
  int*   bsum      = (int*)alloc(1024);
  int*   dead      = (int*)alloc((size_t)N * 4);
  u8*    matched   = (u8*)alloc((size_t)E);
  int*   cluster   = (int*)alloc((size_t)N * 4);
  int*   new_batch = (int*)alloc((size_t)N * 4);
  float* xs_part   = (float*)alloc((size_t)4 * 64 * 512 * 4);  // per-stage partials
  float* gn_part   = (float*)alloc((size_t)64 * 8 * 4);
  float* small     = (float*)alloc(16384);
  size_t zbytes = (size_t)(w - zstart);
  if ((size_t)(w - (char*)d_ws) > ws_size) return;  // fail loudly

  int*   col = colbuf;         // CSR src per slot
  int*   eid = colbuf + E;     // CSR original-edge id per slot
  float* aN  = (float*)listA;  // alias: dots dead before ns/nd used
  float* bN  = (float*)listB;
  float* uB  = agg;            // u for all convs (agg phase-disjoint)
  u64*   keyA = (u64*)agg;     // score/key output + match ping-pong
  u64*   keyB = keyA + E;
  u32*   sdA  = (u32*)(keyB + E);
  u32*   sdB  = sdA + E;
  u64*   bcur0 = (u64*)(sdB + E);  // round-0 global minima (tail of agg)
  u64*   table = (u64*)agg;    // hash (after match, before conv3)
  int*   srcE = pos;           // alias: pos re-filled later by 2nd scan_out

  float* gccnt  = small;                 // [8]
  int*   nclusP = (int*)(small + 16);
  int*   gposM  = (int*)(small + 32);    // [8] alive-list counters (zeroed)

  const int TB = 256;
  const int gN = (N + TB - 1) / TB;
  const int gE = (E + TB - 1) / TB;
  const int gE1k = (E + 1023) >> 10;
  const int gNw = (int)(((size_t)N * 64 + TB - 1) / TB);  // wave per node
  const int swz = (gNw % 8 == 0) ? 1 : 0;
  const int nc = N + 2;
  const int nb = (nc + 1023) / 1024;

  hipMemsetAsync(zstart, 0, zbytes, stream);
  hipMemsetAsync(bcur0, 0xFF, (size_t)N * 8, stream);

  // ---- CSR for original edges ----
  k_count<<<gE1k, TB, 0, stream>>>(dst, cnt, E);
  k_scan_sums<<<nb, TB, 0, stream>>>(cnt, bsum, nc);
  k_scan_tops<<<1, 128, 0, stream>>>(bsum, nb);
  k_scan_out<<<nb, TB, 0, stream>>>(cnt, bsum, rowptr, pos, nc);
  k_fill<<<gE, TB, 0, stream>>>(src, dst, pos, col, eid, E, N);

  // ---- conv1 (F=128 -> 64) ----
  k_transform2<128><<<gN, TB, 0, stream>>>(x, w_rel1, w_root1, b_rel1, nullptr, r, uB, N);
  k_gfin2<<<gNw, TB, 0, stream>>>(r, uB, rowptr, col, batch, gP, nullptr, hA,
                                  nullptr, nullptr, nullptr, xs_part + 0 * 32768, gn_part, N, swz);

  // ---- conv2 (64 -> 64, + score dots) ----
  k_transform2<64><<<gN, TB, 0, stream>>>(hA, w_rel2, w_root2, b_rel2, nullptr, r, uB, N);
  k_gfin2<<<gNw, TB, 0, stream>>>(r, uB, rowptr, col, batch, gP, nullptr, hB,
                                  pool_w, aN, bN, xs_part + 1 * 32768, nullptr, N, swz);

  // ---- scoring (CSR order) + grid-wide matching round 0 ----
  k_score_csr<<<gN, TB, 0, stream>>>(aN, bN, pool_b, rowptr, col, eid, gP,
                                     score, keyA, sdA, bcur0, N);
  k_match0<<<gN, TB, 0, stream>>>(rowptr, gP, keyA, sdA, bcur0, matched, dead, N);
  k_list0<<<gN, TB, 0, stream>>>(rowptr, gP, keyA, sdA, dead, keyB, sdB, gposM, N);

  // ---- greedy matching rounds 1+ (per-graph WG, LDS state, wave tail) ----
  k_match_wg<<<8, 1024, 0, stream>>>(rowptr, gP, gposM, keyB, keyA, sdB, sdA,
                                     dead, matched, N);

  // ---- clusters (two-phase), new_x (+hash init), dedup + pooled CSR ----
  k_build2<<<512, TB, 0, stream>>>(matched, src, dst, batch, dead, cluster, new_batch,
                                   srcE, nclusP, gccnt, cnt, E, N, nc);
  k_newx<<<gNw, TB, 0, stream>>>(srcE, src, dst, score, nclusP, hB, hA, table, N);
  k_dedup<<<gE, TB, 0, stream>>>(src, dst, cluster, table, listA, listB, cnt, E, N);
  k_scan_sums<<<nb, TB, 0, stream>>>(cnt, bsum, nc);
  k_scan_tops<<<1, 128, 0, stream>>>(bsum, nb);
  k_scan_out<<<nb, TB, 0, stream>>>(cnt, bsum, rowptr, pos, nc);
  k_fill<<<gE, TB, 0, stream>>>(listA, listB, pos, col, nullptr, E, N);

  // ---- conv3 (64 -> 64, pooled) ----
  k_transform2<64><<<gN, TB, 0, stream>>>(hA, w_rel3, w_root3, b_rel3, nclusP, r, uB, N);
  k_gfin2<<<gNw, TB, 0, stream>>>(r, uB, rowptr, col, new_batch, gP, nclusP, hB,
                                  nullptr, nullptr, nullptr, xs_part + 2 * 32768, nullptr, N, 0);

  // ---- conv4 (64 -> 64, pooled) ----
  k_transform2<64><<<gN, TB, 0, stream>>>(hB, w_rel4, w_root4, b_rel4, nclusP, r, uB, N);
  k_gfin2<<<gNw, TB, 0, stream>>>(r, uB, rowptr, col, new_batch, gP, nclusP, hA,
                                  nullptr, nullptr, nullptr, xs_part + 3 * 32768, nullptr, N, 0);

  // ---- head ----
  k_head<<<1, TB, 0, stream>>>(xs_part, gn_part, gccnt, lin1_w, lin1_b, lin2_w, lin2_b, gP, out, C);
}

// Round 11
// 1418.553 us; speedup vs baseline: 1.3933x; 1.1017x over previous
//
#include <hip/hip_runtime.h>
#include <stdint.h>

typedef unsigned long long u64;
typedef unsigned int u32;
typedef unsigned char u8;

// ---------------------------------------------------------------------------
// EdgePool GNN pipeline.  N=100000, E=800000, F=128, H=64, G=8, C=10. f32.
// R1 two-stage gmp · R2 dst-CSR gather · R4 match state in LDS · R5 XCD
// swizzle + epoch bcur + no-max softmax · R7 wave-per-node gfin2 + partial
// gmp flush + two-phase build · R8 CSR-ordered scoring · R9 grid-wide
// matching round 0 + single-wave LDS tail.
// R10: k_transform2 de-spilled. R6's dual-GEMM held 128 live accumulators;
//      compiler capped VGPR at 64 and spilled ~250MB/dispatch to scratch
//      (WRITE_SIZE 303MB vs 51MB legit, VALUBusy 27%, 220us x4). Now two
//      sequential 64-acc phases (rel -> r, barrier, re-stage ws, root -> u):
//      ~85 live regs (proven non-spilling shape), LDS halved, x re-read hits
//      L2. FP order per output unchanged.
// ---------------------------------------------------------------------------

// Phase 0: r = x@w_rel^T.  Phase 1: u = x@w_root^T + bias.  One LDS buffer,
// re-staged between phases; all threads participate in barriers.
template <int K>
__global__ __launch_bounds__(256) void k_transform2(
    const float* __restrict__ x, const float* __restrict__ wrel,
    const float* __restrict__ wroot, const float* __restrict__ bias,
    const int* __restrict__ nvP, float* __restrict__ r,
    float* __restrict__ u, int n) {
  __shared__ float ws[64 * K];
  int node = blockIdx.x * blockDim.x + threadIdx.x;
  bool act = node < n;
  if (act && nvP && node >= *nvP) act = false;
  const float* xr = x + (size_t)node * K;
#pragma unroll
  for (int p = 0; p < 2; ++p) {
    const float* wsrc = p ? wroot : wrel;
    __syncthreads();  // previous phase's ws readers done
    for (int i = threadIdx.x; i < 64 * K; i += 256) ws[i] = wsrc[i];
    __syncthreads();
    if (act) {
      float acc[64];
#pragma unroll
      for (int o = 0; o < 64; ++o) acc[o] = p ? bias[o] : 0.f;
      for (int k = 0; k < K; k += 4) {
        float4 xv = *reinterpret_cast<const float4*>(xr + k);
#pragma unroll
        for (int o = 0; o < 64; ++o) {
          float4 wv = *reinterpret_cast<const float4*>(&ws[o * K + k]);
          acc[o] = fmaf(xv.x, wv.x, acc[o]);
          acc[o] = fmaf(xv.y, wv.y, acc[o]);
          acc[o] = fmaf(xv.z, wv.z, acc[o]);
          acc[o] = fmaf(xv.w, wv.w, acc[o]);
        }
      }
      float4* outp = reinterpret_cast<float4*>((p ? u : r) + (size_t)node * 64);
#pragma unroll
      for (int o = 0; o < 16; ++o)
        outp[o] = make_float4(acc[4 * o], acc[4 * o + 1], acc[4 * o + 2], acc[4 * o + 3]);
    }
  }
}

// dst-degree count; 1024-edge chunks
__global__ void k_count(const int* __restrict__ dst, int* __restrict__ cnt, int e) {
  int base = blockIdx.x << 10;
#pragma unroll
  for (int k = 0; k < 4; ++k) {
    int i = base + k * 256 + threadIdx.x;
    if (i < e) atomicAdd(&cnt[dst[i]], 1);
  }
}

// ---- scan over nc ints ----
__global__ void k_scan_sums(const int* __restrict__ in, int* __restrict__ bsum, int n) {
  __shared__ int sd[256];
  int base = blockIdx.x << 10;
  int s = 0;
  for (int j = threadIdx.x; j < 1024; j += 256) {
    int id = base + j;
    s += (id < n) ? in[id] : 0;
  }
  sd[threadIdx.x] = s;
  __syncthreads();
  for (int w = 128; w > 0; w >>= 1) {
    if (threadIdx.x < w) sd[threadIdx.x] += sd[threadIdx.x + w];
    __syncthreads();
  }
  if (threadIdx.x == 0) bsum[blockIdx.x] = sd[0];
}
__global__ void k_scan_tops(int* __restrict__ bsum, int nb) {
  __shared__ int sd[128];
  int tid = threadIdx.x;
  int v = (tid < nb) ? bsum[tid] : 0;
  sd[tid] = v;
  __syncthreads();
  for (int off = 1; off < 128; off <<= 1) {
    int add = (tid >= off) ? sd[tid - off] : 0;
    __syncthreads();
    sd[tid] += add;
    __syncthreads();
  }
  if (tid < nb) bsum[tid] = sd[tid] - v;  // exclusive
}
__global__ void k_scan_out(const int* __restrict__ in, const int* __restrict__ bsum,
                           int* __restrict__ rowptr, int* __restrict__ pos, int n) {
  __shared__ int sd[256];
  int base = blockIdx.x << 10;
  int i0 = base + threadIdx.x * 4;
  int v0 = 0, v1 = 0, v2 = 0, v3 = 0;
  if (i0 < n) v0 = in[i0];
  if (i0 + 1 < n) v1 = in[i0 + 1];
  if (i0 + 2 < n) v2 = in[i0 + 2];
  if (i0 + 3 < n) v3 = in[i0 + 3];
  sd[threadIdx.x] = v0 + v1 + v2 + v3;
  __syncthreads();
  for (int off = 1; off < 256; off <<= 1) {
    int add = (threadIdx.x >= off) ? sd[threadIdx.x - off] : 0;
    __syncthreads();
    sd[threadIdx.x] += add;
    __syncthreads();
  }
  int excl = bsum[blockIdx.x] + (threadIdx.x ? sd[threadIdx.x - 1] : 0);
  if (i0 < n) { rowptr[i0] = excl; pos[i0] = excl; }
  excl += v0;
  if (i0 + 1 < n) { rowptr[i0 + 1] = excl; pos[i0 + 1] = excl; }
  excl += v1;
  if (i0 + 2 < n) { rowptr[i0 + 2] = excl; pos[i0 + 2] = excl; }
  excl += v2;
  if (i0 + 3 < n) { rowptr[i0 + 3] = excl; pos[i0 + 3] = excl; }
}

// CSR fill: col = src, eid = original edge index
__global__ void k_fill(const int* __restrict__ src, const int* __restrict__ dst,
                       int* __restrict__ pos, int* __restrict__ col,
                       int* __restrict__ eid, int e, int n) {
  int i = blockIdx.x * blockDim.x + threadIdx.x;
  if (i >= e) return;
  int d = dst[i];
  if (d >= n) return;  // sentinel (pooled duplicates)
  int j = atomicAdd(&pos[d], 1);
  col[j] = src[i];
  if (eid) eid[j] = i;
}

// R7 fused conv tail: wave-per-node gather + mean + relu + h-write (+dots),
// gmp accumulated in LDS, flushed to 64 partial buffers (presence-masked).
__global__ void k_gfin2(const float* __restrict__ r, const float* __restrict__ u,
                        const int* __restrict__ rowptr, const int* __restrict__ col,
                        const int* __restrict__ batch, const int* __restrict__ gP,
                        const int* __restrict__ nvP, float* __restrict__ h,
                        const float* __restrict__ pw, float* __restrict__ aN,
                        float* __restrict__ bN, float* __restrict__ xs_part /*[64][512]*/,
                        float* __restrict__ gn_part /*[64][8] or null*/, int n, int swz) {
  __shared__ float sacc[512];
  __shared__ float scnt8[8];
  __shared__ float pws[128];
  __shared__ int pres;
  int G = *gP;
  int nv = nvP ? *nvP : n;
  if (nv > n) nv = n;
  for (int i = threadIdx.x; i < 512; i += 256) sacc[i] = 0.f;
  if (threadIdx.x < 8) scnt8[threadIdx.x] = 0.f;
  if (threadIdx.x == 0) pres = 0;
  if (pw && threadIdx.x < 128) pws[threadIdx.x] = pw[threadIdx.x];
  __syncthreads();
  int b = blockIdx.x;
  if (swz) { int chunk = gridDim.x >> 3; b = (b & 7) * chunk + (b >> 3); }
  int lane = threadIdx.x & 63, w = threadIdx.x >> 6;
  int node = b * 4 + w;
  if (node < nv) {
    int bg = rowptr[node], e2 = rowptr[node + 1];
    float s = 0.f;
    for (int j = bg; j < e2; ++j) s += r[(size_t)col[j] * 64 + lane];
    int deg = e2 - bg;
    float inv = deg > 0 ? 1.f / (float)deg : 0.f;
    float v = fmaf(s, inv, u[(size_t)node * 64 + lane]);
    v = v > 0.f ? v : 0.f;
    h[(size_t)node * 64 + lane] = v;
    if (pw) {
      float d1 = v * pws[lane];
      float d2 = v * pws[64 + lane];
#pragma unroll
      for (int off = 32; off > 0; off >>= 1) {
        d1 += __shfl_down(d1, off, 64);
        d2 += __shfl_down(d2, off, 64);
      }
      if (lane == 0) { aN[node] = d1; bN[node] = d2; }
    }
    int g = batch[node];
    if ((unsigned)g < 8u && g < G) {
      atomicAdd(&sacc[g * 64 + lane], v);
      if (lane == 0) {
        atomicOr(&pres, 1 << g);
        if (gn_part) atomicAdd(&scnt8[g], 1.f);
      }
    }
  }
  __syncthreads();
  int pm = pres;
  if (!pm) return;
  int buf = blockIdx.x & 63;
  float* xp = xs_part + buf * 512;
  for (int i = threadIdx.x; i < 512; i += 256) {
    if ((pm >> (i >> 6)) & 1) {
      float s2 = sacc[i];
      if (s2 != 0.f) atomicAdd(&xp[i], s2);
    }
  }
  if (gn_part && threadIdx.x < 8) {
    float c = scnt8[threadIdx.x];
    if (c != 0.f) atomicAdd(&gn_part[buf * 8 + threadIdx.x], c);
  }
}

// R8/R9: CSR-ordered scoring + round-0 priority claim into global bcur0.
__global__ void k_score_csr(const float* __restrict__ aN, const float* __restrict__ bN,
                            const float* __restrict__ pbp, const int* __restrict__ rowptr,
                            const int* __restrict__ col, const int* __restrict__ eid,
                            const int* __restrict__ gP, float* __restrict__ score,
                            u64* __restrict__ keyA, u32* __restrict__ sdA,
                            u64* __restrict__ bcur0, int N) {
  int d = blockIdx.x * blockDim.x + threadIdx.x;
  if (d >= N) return;
  int b = rowptr[d], e2 = rowptr[d + 1];
  if (b == e2) return;
  float bd = bN[d] + pbp[0];
  float den = 0.f;
  for (int j = b; j < e2; ++j) den += expf(aN[col[j]] + bd);
  int per = N / *gP;
  int g = d / per;
  int base = g * per;
  u32 dl = (u32)(d - base);
  u64 rmin = ~0ull;
  for (int j = b; j < e2; ++j) {
    int s = col[j];
    int ei = eid[j];
    float sc = expf(aN[s] + bd) / den + 0.5f;
    score[ei] = sc;
    u64 k = ((u64)(u32)(~__float_as_uint(sc)) << 20) | (u32)ei;
    keyA[j] = k;
    sdA[j] = ((u32)(s - base) << 16) | dl;
    atomicMin(&bcur0[s], k);
    if (k < rmin) rmin = k;
  }
  atomicMin(&bcur0[d], rmin);
}

// R9: grid-wide round-0 match test (bcur0 read-only -> deterministic).
__global__ void k_match0(const int* __restrict__ rowptr, const int* __restrict__ gP,
                         const u64* __restrict__ keyA, const u32* __restrict__ sdA,
                         const u64* __restrict__ bcur0, u8* __restrict__ matched,
                         int* __restrict__ dead, int N) {
  int d = blockIdx.x * blockDim.x + threadIdx.x;
  if (d >= N) return;
  int b = rowptr[d], e2 = rowptr[d + 1];
  if (b == e2) return;
  int per = N / *gP;
  int base = (d / per) * per;
  u64 kd = bcur0[d];
  for (int j = b; j < e2; ++j) {
    u64 k = keyA[j];
    int gs = base + (int)(sdA[j] >> 16);
    if (bcur0[gs] == k && (gs == d || kd == k)) {
      matched[(u32)(k & 0xFFFFF)] = 1;
      dead[gs] = 1;
      dead[d] = 1;
    }
  }
}

// R9: grid-wide alive-list build (dead stable/read-only here).
__global__ void k_list0(const int* __restrict__ rowptr, const int* __restrict__ gP,
                        const u64* __restrict__ keyA, const u32* __restrict__ sdA,
                        const int* __restrict__ dead, u64* __restrict__ keyB,
                        u32* __restrict__ sdB, int* __restrict__ gposM, int N) {
  __shared__ int scnt[8], sbase[8];
  if (threadIdx.x < 8) scnt[threadIdx.x] = 0;
  __syncthreads();
  int d = blockIdx.x * blockDim.x + threadIdx.x;
  int g = -1, b = 0, e2 = 0, base = 0, myn = 0, rank = 0;
  if (d < N && !dead[d]) {
    b = rowptr[d]; e2 = rowptr[d + 1];
    if (b < e2) {
      int per = N / *gP;
      g = d / per; base = g * per;
      for (int j = b; j < e2; ++j)
        if (!dead[base + (int)(sdA[j] >> 16)]) ++myn;
      if (myn) rank = atomicAdd(&scnt[g], myn);
    }
  }
  __syncthreads();
  if (threadIdx.x < 8 && scnt[threadIdx.x])
    sbase[threadIdx.x] = atomicAdd(&gposM[threadIdx.x], scnt[threadIdx.x]);
  __syncthreads();
  if (g < 0 || !myn) return;
  int off = rowptr[base] + sbase[g] + rank;
  for (int j = b; j < e2; ++j) {
    if (!dead[base + (int)(sdA[j] >> 16)]) {
      keyB[off] = keyA[j];
      sdB[off] = sdA[j];
      ++off;
    }
  }
}

// Per-graph exact greedy matching from round 1. Compacted global rounds
// (R5 structure) + single-wave LDS tail at alive<=WAVECAP (no barriers;
// __threadfence_block orders LDS between phases; in-register compaction).
#define PERMAX 12544
#define WAVECAP 2048
__global__ __launch_bounds__(1024) void k_match_wg(
    const int* __restrict__ rowptr, const int* __restrict__ gP,
    const int* __restrict__ gposM,
    u64* __restrict__ keyB, u64* __restrict__ keyA,
    u32* __restrict__ sdB, u32* __restrict__ sdA,
    int* __restrict__ dead, u8* __restrict__ matched, int N) {
  __shared__ u64 bcur[PERMAX];
  __shared__ u8 dead_s[PERMAX];
  __shared__ u64 tkey[WAVECAP];
  __shared__ u32 tsd[WAVECAP];
  __shared__ int lcnt;
  int G = *gP;
  int g = blockIdx.x;
  if (g >= G) return;
  int per = N / G;
  if (per > PERMAX) per = PERMAX;
  int base = g * per;
  int re = rowptr[base];
  int n = gposM[g];
  int tid = threadIdx.x, lane = tid & 63;
  for (int i = tid; i < per; i += 1024) {
    bcur[i] = ~0ull;
    dead_s[i] = dead[base + i] ? 1 : 0;
  }
  if (tid == 0) lcnt = 0;
  __syncthreads();
  u64* kin = keyB + re; u64* kout = keyA + re;
  u32* sin_ = sdB + re; u32* sout = sdA + re;
  for (int round = 1; n > 0 && round < 4000; ++round) {
    u64 etag = (u64)(4095 - round) << 52;
    // Phase A: claim minima, ballot-compact (+ shadow into LDS when small)
    for (int i = tid; i - lane < n; i += 1024) {
      bool inb = i < n;
      u32 sd = 0; u64 k = 0;
      if (inb) { sd = sin_[i]; k = kin[i]; }
      int s = sd >> 16, d = sd & 0xffff;
      bool alive = inb && !(dead_s[s] | dead_s[d]);
      if (alive) {
        u64 val = etag | k;
        if (val < bcur[s]) atomicMin(&bcur[s], val);
        if (d != s && val < bcur[d]) atomicMin(&bcur[d], val);
      }
      u64 m = __ballot(alive);
      if (m) {
        int lead = __ffsll((long long)m) - 1;
        int bse = 0;
        if (lane == lead) bse = atomicAdd(&lcnt, __popcll(m));
        bse = __shfl(bse, lead, 64);
        if (alive) {
          int j = bse + __popcll(m & ((1ull << lane) - 1ull));
          kout[j] = k;
          sout[j] = sd;
          if (j < WAVECAP) { tkey[j] = k; tsd[j] = sd; }
        }
      }
    }
    __syncthreads();
    int n2 = lcnt;
    if (n2 == 0) break;
    bool totail = (n2 <= WAVECAP);
    // Phase B: locally-dominant edges match
    for (int i = tid; i < n2; i += 1024) {
      u32 sd; u64 k;
      if (totail) { sd = tsd[i]; k = tkey[i]; }
      else { sd = sout[i]; k = kout[i]; }
      int s = sd >> 16, d = sd & 0xffff;
      u64 val = etag | k;
      if (bcur[s] == val && (d == s || bcur[d] == val)) {
        matched[(u32)(k & 0xFFFFF)] = 1;
        dead_s[s] = 1;
        dead_s[d] = 1;
      }
    }
    if (tid == 0) lcnt = 0;
    __syncthreads();
    if (totail) {
      if (tid < 64) {
        // single-wave tail: rounds at LDS latency, no block barriers
        int nt = n2;
        int rr = round + 1;
        while (nt > 0 && rr < 4000) {
          u64 et2 = (u64)(4095 - rr) << 52;
          for (int i = lane; i < nt; i += 64) {
            u32 sd = tsd[i];
            int s = sd >> 16, d = sd & 0xffff;
            if (dead_s[s] | dead_s[d]) continue;
            u64 val = et2 | tkey[i];
            if (val < bcur[s]) atomicMin(&bcur[s], val);
            if (d != s && val < bcur[d]) atomicMin(&bcur[d], val);
          }
          __threadfence_block();
          int wc = 0;
          for (int i0 = 0; i0 < nt; i0 += 64) {
            int i = i0 + lane;
            u32 sd = 0; u64 k = 0;
            bool have = i < nt;
            if (have) { sd = tsd[i]; k = tkey[i]; }
            int s = sd >> 16, d = sd & 0xffff;
            bool alive = false;
            if (have && !(dead_s[s] | dead_s[d])) {
              u64 val = et2 | k;
              if (bcur[s] == val && (d == s || bcur[d] == val)) {
                matched[(u32)(k & 0xFFFFF)] = 1;
                dead_s[s] = 1;
                dead_s[d] = 1;
              } else {
                alive = true;
              }
            }
            u64 m = __ballot(alive);
            int idx = wc + __popcll(m & ((1ull << lane) - 1ull));
            if (alive) { tkey[idx] = k; tsd[idx] = sd; }
            wc += (int)__popcll(m);
          }
          nt = wc;
          ++rr;
          __threadfence_block();
        }
      }
      __syncthreads();
      break;
    }
    u64* tk = kin; kin = kout; kout = tk;
    u32* ts = sin_; sin_ = sout; sout = ts;
    n = n2;
  }
  __syncthreads();
  for (int i = tid; i < per; i += 1024) dead[base + i] = dead_s[i];
}

// R7 two-phase cluster build (512 blocks); also zeroes cnt.
__global__ void k_build2(const u8* __restrict__ matched, const int* __restrict__ src,
                         const int* __restrict__ dst, const int* __restrict__ batch,
                         const int* __restrict__ dead, int* __restrict__ cluster,
                         int* __restrict__ new_batch, int* __restrict__ srcE,
                         int* __restrict__ nclus, float* __restrict__ gccnt,
                         int* __restrict__ cnt, int e, int n, int nc) {
  __shared__ int c_cnt, c_off, basep;
  __shared__ int sc[8];
  if (threadIdx.x == 0) { c_cnt = 0; c_off = 0; basep = 0; }
  if (threadIdx.x < 8) sc[threadIdx.x] = 0;
  __syncthreads();
  int nbk = gridDim.x;
  for (int i = blockIdx.x * blockDim.x + threadIdx.x; i < nc; i += nbk * blockDim.x) cnt[i] = 0;
  int ec = (e + nbk - 1) / nbk, es = blockIdx.x * ec, ee = es + ec; if (ee > e) ee = e;
  int nk = (n + nbk - 1) / nbk, ns = blockIdx.x * nk, ne = ns + nk; if (ne > n) ne = n;
  int my = 0;
  for (int i = es + threadIdx.x; i < ee; i += blockDim.x) if (matched[i]) ++my;
  for (int i = ns + threadIdx.x; i < ne; i += blockDim.x) if (!dead[i]) ++my;
  if (my) atomicAdd(&c_cnt, my);
  __syncthreads();
  if (threadIdx.x == 0 && c_cnt) basep = atomicAdd(nclus, c_cnt);
  __syncthreads();
  int bse = basep;
  for (int i = es + threadIdx.x; i < ee; i += blockDim.x) {
    if (!matched[i]) continue;
    int c = bse + atomicAdd(&c_off, 1);
    int s = src[i], d = dst[i];
    cluster[s] = c;
    cluster[d] = c;
    srcE[c] = i;
    int g = batch[s];
    new_batch[c] = g;
    if ((unsigned)g < 8u) atomicAdd(&sc[g], 1);
  }
  for (int i = ns + threadIdx.x; i < ne; i += blockDim.x) {
    if (dead[i]) continue;
    int c = bse + atomicAdd(&c_off, 1);
    cluster[i] = c;
    srcE[c] = ~i;  // singleton: encoded node
    int g = batch[i];
    new_batch[c] = g;
    if ((unsigned)g < 8u) atomicAdd(&sc[g], 1);
  }
  __syncthreads();
  if (threadIdx.x < 8 && sc[threadIdx.x] > 0)
    atomicAdd(&gccnt[threadIdx.x], (float)sc[threadIdx.x]);
}

#define HBITS 21
#define HMASK ((1u << HBITS) - 1u)

// cluster-driven new_x (wave per cluster) + hash-table init prologue.
__global__ void k_newx(const int* __restrict__ srcE, const int* __restrict__ src,
                       const int* __restrict__ dst, const float* __restrict__ score,
                       const int* __restrict__ nclusP, const float* __restrict__ h2,
                       float* __restrict__ new_x, u64* __restrict__ table, int n) {
  int idx = blockIdx.x * blockDim.x + threadIdx.x;
  if (idx < (1 << HBITS)) table[idx] = ~0ull;
  int c = idx >> 6;
  int lane = idx & 63;
  if (c >= n || c >= *nclusP) return;
  int v = srcE[c];
  float val;
  if (v >= 0) {
    int s = src[v], d = dst[v];
    val = h2[(size_t)s * 64 + lane];
    if (d != s) val += h2[(size_t)d * 64 + lane];
    val *= score[v];
  } else {
    val = h2[(size_t)(~v) * 64 + lane];
  }
  new_x[(size_t)c * 64 + lane] = val;
}

// coalesce(cluster[edge_index]): hash-dedup; dups -> sentinel n; counts kept.
__global__ void k_dedup(const int* __restrict__ src, const int* __restrict__ dst,
                        const int* __restrict__ cluster, u64* __restrict__ table,
                        int* __restrict__ ns, int* __restrict__ nd,
                        int* __restrict__ cnt, int e, int n) {
  int i = blockIdx.x * blockDim.x + threadIdx.x;
  if (i >= e) return;
  int cs_ = cluster[src[i]], cd_ = cluster[dst[i]];
  u64 kk = (u64)cs_ * (u64)(n + 1) + (u64)cd_;
  u32 pos = (u32)((kk * 0x9E3779B97F4A7C15ull) >> 43) & HMASK;
  while (true) {
    u64 old = atomicCAS(&table[pos], ~0ull, kk);
    if (old == ~0ull) {
      ns[i] = cs_; nd[i] = cd_;
      atomicAdd(&cnt[cd_], 1);
      return;
    }
    if (old == kk) { ns[i] = n; nd[i] = n; return; }
    pos = (pos + 1) & HMASK;
  }
}

// JK cat (partial-buffer reduce) + lin1 + relu + lin2 + log_softmax.
__global__ void k_head(const float* __restrict__ xs_part /*[4][64][512]*/,
                       const float* __restrict__ gn_part /*[64][8]*/,
                       const float* __restrict__ gccnt,
                       const float* __restrict__ l1w, const float* __restrict__ l1b,
                       const float* __restrict__ l2w, const float* __restrict__ l2b,
                       const int* __restrict__ gP, float* __restrict__ out, int C) {
  __shared__ float z[8][256];
  __shared__ float z1[8][64];
  __shared__ float z2[8][16];
  __shared__ float gnc[8];
  int G = *gP;
  int tid = threadIdx.x;
  if (tid < 8) {
    float s = 0.f;
    for (int b = 0; b < 64; ++b) s += gn_part[b * 8 + tid];
    gnc[tid] = s;
  }
  __syncthreads();
  int p = tid >> 6, f = tid & 63;
  for (int g = 0; g < G; ++g) {
    const float* xp = xs_part + (size_t)p * 64 * 512;
    float s = 0.f;
    for (int b = 0; b < 64; ++b) s += xp[b * 512 + g * 64 + f];
    float c = (p < 2) ? gnc[g] : gccnt[g];
    if (c < 1.f) c = 1.f;
    z[g][tid] = s / c;
  }
  __syncthreads();
  for (int idx = tid; idx < G * 64; idx += blockDim.x) {
    int g = idx >> 6, o = idx & 63;
    float a = l1b[o];
    for (int k = 0; k < 256; ++k) a = fmaf(z[g][k], l1w[o * 256 + k], a);
    z1[g][o] = a > 0.f ? a : 0.f;
  }
  __syncthreads();
  for (int idx = tid; idx < G * C; idx += blockDim.x) {
    int g = idx / C, c = idx % C;
    float a = l2b[c];
    for (int k = 0; k < 64; ++k) a = fmaf(z1[g][k], l2w[c * 64 + k], a);
    z2[g][c] = a;
  }
  __syncthreads();
  if (tid < G) {
    float m = z2[tid][0];
    for (int c = 1; c < C; ++c) m = fmaxf(m, z2[tid][c]);
    float s = 0.f;
    for (int c = 0; c < C; ++c) s += expf(z2[tid][c] - m);
    float lse = m + logf(s);
    for (int c = 0; c < C; ++c) out[tid * C + c] = z2[tid][c] - lse;
  }
}

extern "C" void kernel_launch(void* const* d_in, const int* in_sizes, int n_in,
                              void* d_out, int out_size, void* d_ws, size_t ws_size,
                              hipStream_t stream) {
  const float* x       = (const float*)d_in[0];
  const int*   ei      = (const int*)d_in[1];
  const int*   batch   = (const int*)d_in[2];
  const float* w_rel1  = (const float*)d_in[3];
  const float* b_rel1  = (const float*)d_in[4];
  const float* w_root1 = (const float*)d_in[5];
  const float* w_rel2  = (const float*)d_in[6];
  const float* b_rel2  = (const float*)d_in[7];
  const float* w_root2 = (const float*)d_in[8];
  const float* w_rel3  = (const float*)d_in[9];
  const float* b_rel3  = (const float*)d_in[10];
  const float* w_root3 = (const float*)d_in[11];
  const float* w_rel4  = (const float*)d_in[12];
  const float* b_rel4  = (const float*)d_in[13];
  const float* w_root4 = (const float*)d_in[14];
  const float* pool_w  = (const float*)d_in[15];
  const float* pool_b  = (const float*)d_in[16];
  const float* lin1_w  = (const float*)d_in[17];
  const float* lin1_b  = (const float*)d_in[18];
  const float* lin2_w  = (const float*)d_in[19];
  const float* lin2_b  = (const float*)d_in[20];
  const int*   gP      = (const int*)d_in[21];
  float* out = (float*)d_out;

  const int N = in_sizes[2];
  const int E = in_sizes[1] / 2;
  const int C = in_sizes[20];
  const int* src = ei;
  const int* dst = ei + E;

  // ---- workspace layout ----
  char* w = (char*)d_ws;
  auto alloc = [&](size_t bytes) -> char* {
    char* p = w;
    w += (bytes + 255) & ~(size_t)255;
    return p;
  };
  float* r      = (float*)alloc((size_t)N * 64 * 4);
  float* agg    = (float*)alloc((size_t)(N + 1) * 64 * 4);  // u / match lists / hash
  float* hA     = (float*)alloc((size_t)N * 64 * 4);        // h1 -> new_x -> h4
  float* hB     = (float*)alloc((size_t)N * 64 * 4);        // h2 -> h3
  float* score  = (float*)alloc((size_t)E * 4);
  int*   colbuf = (int*)alloc((size_t)E * 8);               // col + eid
  int*   listA  = (int*)alloc((size_t)E * 4);               // aN -> ns
  int*   listB  = (int*)alloc((size_t)E * 4);               // bN -> nd
  int*   rowptr = (int*)alloc((size_t)(N + 2) * 4);
  int*   pos    = (int*)alloc((size_t)(N + 2) * 4);         // also srcE
  char* zstart = w;                                         // zeroed block
  int*   cnt       = (int*)alloc((size_t)(N + 2) * 4);
  int*   bsum      = (int*)alloc(1024);
  int*   dead      = (int*)alloc((size_t)N * 4);
  u8*    matched   = (u8*)alloc((size_t)E);
  int*   cluster   = (int*)alloc((size_t)N * 4);
  int*   new_batch = (int*)alloc((size_t)N * 4);
  float* xs_part   = (float*)alloc((size_t)4 * 64 * 512 * 4);  // per-stage partials
  float* gn_part   = (float*)alloc((size_t)64 * 8 * 4);
  float* small     = (float*)alloc(16384);
  size_t zbytes = (size_t)(w - zstart);
  if ((size_t)(w - (char*)d_ws) > ws_size) return;  // fail loudly

  int*   col = colbuf;         // CSR src per slot
  int*   eid = colbuf + E;     // CSR original-edge id per slot
  float* aN  = (float*)listA;  // alias: dots dead before ns/nd used
  float* bN  = (float*)listB;
  float* uB  = agg;            // u for all convs (agg phase-disjoint)
  u64*   keyA = (u64*)agg;     // score/key output + match ping-pong
  u64*   keyB = keyA + E;
  u32*   sdA  = (u32*)(keyB + E);
  u32*   sdB  = sdA + E;
  u64*   bcur0 = (u64*)(sdB + E);  // round-0 global minima (tail of agg)
  u64*   table = (u64*)agg;    // hash (after match, before conv3)
  int*   srcE = pos;           // alias: pos re-filled later by 2nd scan_out

  float* gccnt  = small;                 // [8]
  int*   nclusP = (int*)(small + 16);
  int*   gposM  = (int*)(small + 32);    // [8] alive-list counters (zeroed)

  const int TB = 256;
  const int gN = (N + TB - 1) / TB;
  const int gE = (E + TB - 1) / TB;
  const int gE1k = (E + 1023) >> 10;
  const int gNw = (int)(((size_t)N * 64 + TB - 1) / TB);  // wave per node
  const int swz = (gNw % 8 == 0) ? 1 : 0;
  const int nc = N + 2;
  const int nb = (nc + 1023) / 1024;

  hipMemsetAsync(zstart, 0, zbytes, stream);
  hipMemsetAsync(bcur0, 0xFF, (size_t)N * 8, stream);

  // ---- CSR for original edges ----
  k_count<<<gE1k, TB, 0, stream>>>(dst, cnt, E);
  k_scan_sums<<<nb, TB, 0, stream>>>(cnt, bsum, nc);
  k_scan_tops<<<1, 128, 0, stream>>>(bsum, nb);
  k_scan_out<<<nb, TB, 0, stream>>>(cnt, bsum, rowptr, pos, nc);
  k_fill<<<gE, TB, 0, stream>>>(src, dst, pos, col, eid, E, N);

  // ---- conv1 (F=128 -> 64) ----
  k_transform2<128><<<gN, TB, 0, stream>>>(x, w_rel1, w_root1, b_rel1, nullptr, r, uB, N);
  k_gfin2<<<gNw, TB, 0, stream>>>(r, uB, rowptr, col, batch, gP, nullptr, hA,
                                  nullptr, nullptr, nullptr, xs_part + 0 * 32768, gn_part, N, swz);

  // ---- conv2 (64 -> 64, + score dots) ----
  k_transform2<64><<<gN, TB, 0, stream>>>(hA, w_rel2, w_root2, b_rel2, nullptr, r, uB, N);
  k_gfin2<<<gNw, TB, 0, stream>>>(r, uB, rowptr, col, batch, gP, nullptr, hB,
                                  pool_w, aN, bN, xs_part + 1 * 32768, nullptr, N, swz);

  // ---- scoring (CSR order) + grid-wide matching round 0 ----
  k_score_csr<<<gN, TB, 0, stream>>>(aN, bN, pool_b, rowptr, col, eid, gP,
                                     score, keyA, sdA, bcur0, N);
  k_match0<<<gN, TB, 0, stream>>>(rowptr, gP, keyA, sdA, bcur0, matched, dead, N);
  k_list0<<<gN, TB, 0, stream>>>(rowptr, gP, keyA, sdA, dead, keyB, sdB, gposM, N);

  // ---- greedy matching rounds 1+ (per-graph WG, LDS state, wave tail) ----
  k_match_wg<<<8, 1024, 0, stream>>>(rowptr, gP, gposM, keyB, keyA, sdB, sdA,
                                     dead, matched, N);

  // ---- clusters (two-phase), new_x (+hash init), dedup + pooled CSR ----
  k_build2<<<512, TB, 0, stream>>>(matched, src, dst, batch, dead, cluster, new_batch,
                                   srcE, nclusP, gccnt, cnt, E, N, nc);
  k_newx<<<gNw, TB, 0, stream>>>(srcE, src, dst, score, nclusP, hB, hA, table, N);
  k_dedup<<<gE, TB, 0, stream>>>(src, dst, cluster, table, listA, listB, cnt, E, N);
  k_scan_sums<<<nb, TB, 0, stream>>>(cnt, bsum, nc);
  k_scan_tops<<<1, 128, 0, stream>>>(bsum, nb);
  k_scan_out<<<nb, TB, 0, stream>>>(cnt, bsum, rowptr, pos, nc);
  k_fill<<<gE, TB, 0, stream>>>(listA, listB, pos, col, nullptr, E, N);

  // ---- conv3 (64 -> 64, pooled) ----
  k_transform2<64><<<gN, TB, 0, stream>>>(hA, w_rel3, w_root3, b_rel3, nclusP, r, uB, N);
  k_gfin2<<<gNw, TB, 0, stream>>>(r, uB, rowptr, col, new_batch, gP, nclusP, hB,
                                  nullptr, nullptr, nullptr, xs_part + 2 * 32768, nullptr, N, 0);

  // ---- conv4 (64 -> 64, pooled) ----
  k_transform2<64><<<gN, TB, 0, stream>>>(hB, w_rel4, w_root4, b_rel4, nclusP, r, uB, N);
  k_gfin2<<<gNw, TB, 0, stream>>>(r, uB, rowptr, col, new_batch, gP, nclusP, hA,
                                  nullptr, nullptr, nullptr, xs_part + 3 * 32768, nullptr, N, 0);

  // ---- head ----
  k_head<<<1, TB, 0, stream>>>(xs_part, gn_part, gccnt, lin1_w, lin1_b, lin2_w, lin2_b, gP, out, C);
}